// Round 1
// baseline (9509.915 us; speedup 1.0000x reference)
//
#include <hip/hip_runtime.h>

#define NEG_SLOPE 0.2f
#define EPSF 1e-16f

// ============================================================ GEMM + alpha
// x:[N,128] row-major, Wl:[128,128], att_s/att_d:[128] (=[4][32] flat)
// h:[N,128], alpha_s/alpha_d:[N,4]
// Block 256 threads computes 64 rows x 128 cols. Thread t: cols 4*(t%32)..+3,
// rows rowBase + (t>>5) + 8j, j=0..7.
__global__ __launch_bounds__(256) void gemm_alpha_kernel(
    const float* __restrict__ x, const float* __restrict__ Wl,
    const float* __restrict__ att_s, const float* __restrict__ att_d,
    float* __restrict__ h, float* __restrict__ alpha_s,
    float* __restrict__ alpha_d, int N)
{
    __shared__ float4 sW[1024];   // [32][128] floats
    __shared__ float4 sX[512];    // [64][32] floats
    const int t = threadIdx.x;
    const int c4 = t & 31;        // float4 column index (cols 4*c4..4*c4+3)
    const int r0 = t >> 5;        // 0..7
    const int rowBase = blockIdx.x * 64;

    float4 acc[8];
#pragma unroll
    for (int j = 0; j < 8; ++j) acc[j] = make_float4(0.f, 0.f, 0.f, 0.f);

    const float* sXs = (const float*)sX;
    const float4* W4 = (const float4*)Wl;
    const float4* x4 = (const float4*)x;

    for (int kb = 0; kb < 128; kb += 32) {
        __syncthreads();
#pragma unroll
        for (int i = 0; i < 4; ++i) {           // W chunk [32][128]
            int f = t + i * 256;
            int k = f >> 5, cc = f & 31;
            sW[f] = W4[(kb + k) * 32 + cc];
        }
#pragma unroll
        for (int i = 0; i < 2; ++i) {           // X chunk [64][32]
            int f = t + i * 256;
            int row = f >> 3, kc = f & 7;
            int grow = rowBase + row;
            float4 v = make_float4(0.f, 0.f, 0.f, 0.f);
            if (grow < N) v = x4[grow * 32 + (kb >> 2) + kc];
            sX[row * 8 + kc] = v;
        }
        __syncthreads();
#pragma unroll
        for (int k = 0; k < 32; ++k) {
            float4 wv = sW[k * 32 + c4];
#pragma unroll
            for (int j = 0; j < 8; ++j) {
                float xv = sXs[(r0 + 8 * j) * 32 + k];
                acc[j].x += xv * wv.x; acc[j].y += xv * wv.y;
                acc[j].z += xv * wv.z; acc[j].w += xv * wv.w;
            }
        }
    }

    const float4 as4 = ((const float4*)att_s)[c4];
    const float4 ad4 = ((const float4*)att_d)[c4];
    const int head = c4 >> 3;

#pragma unroll
    for (int j = 0; j < 8; ++j) {
        int row = rowBase + r0 + 8 * j;
        if (row >= N) continue;                 // uniform over each 8-lane group
        float4 a = acc[j];
        ((float4*)(h + row * 128))[c4] = a;
        float ps = a.x * as4.x + a.y * as4.y + a.z * as4.z + a.w * as4.w;
        float pd = a.x * ad4.x + a.y * ad4.y + a.z * ad4.z + a.w * ad4.w;
        ps += __shfl_down(ps, 4, 8); ps += __shfl_down(ps, 2, 8); ps += __shfl_down(ps, 1, 8);
        pd += __shfl_down(pd, 4, 8); pd += __shfl_down(pd, 2, 8); pd += __shfl_down(pd, 1, 8);
        if ((c4 & 7) == 0) {
            alpha_s[row * 4 + head] = ps;
            alpha_d[row * 4 + head] = pd;
        }
    }
}

// ============================================================ layer init
// out[n][c] = b[c]; s[n][h] = 0
__global__ __launch_bounds__(256) void init_layer_kernel(
    float* __restrict__ out, float* __restrict__ s,
    const float* __restrict__ b, int N)
{
    int i = blockIdx.x * 256 + threadIdx.x;
    if (i < N * 128) out[i] = b[i & 127];
    if (i < N * 4) s[i] = 0.f;
}

// ============================================================ softmax denom
__global__ __launch_bounds__(256) void edge_denom_kernel(
    const int* __restrict__ ei, int E, int N,
    const float* __restrict__ alpha_s, const float* __restrict__ alpha_d,
    float* __restrict__ s)
{
    int idx = blockIdx.x * 256 + threadIdx.x;
    int Etot = E + N;
    if (idx >= Etot) return;
    int src, dst;
    if (idx < E) { src = ei[idx]; dst = ei[E + idx]; }
    else { src = dst = idx - E; }
    float4 as = ((const float4*)alpha_s)[src];
    float4 ad = ((const float4*)alpha_d)[dst];
    float e0 = as.x + ad.x, e1 = as.y + ad.y, e2 = as.z + ad.z, e3 = as.w + ad.w;
    e0 = e0 > 0.f ? e0 : NEG_SLOPE * e0;
    e1 = e1 > 0.f ? e1 : NEG_SLOPE * e1;
    e2 = e2 > 0.f ? e2 : NEG_SLOPE * e2;
    e3 = e3 > 0.f ? e3 : NEG_SLOPE * e3;
    float* sp = s + dst * 4;
    unsafeAtomicAdd(sp + 0, __expf(e0));
    unsafeAtomicAdd(sp + 1, __expf(e1));
    unsafeAtomicAdd(sp + 2, __expf(e2));
    unsafeAtomicAdd(sp + 3, __expf(e3));
}

// ============================================================ aggregate
// 32 lanes per edge; lane l handles channels 4l..4l+3 (head = l>>3)
__global__ __launch_bounds__(256) void edge_agg_kernel(
    const int* __restrict__ ei, int E, int N,
    const float* __restrict__ alpha_s, const float* __restrict__ alpha_d,
    const float* __restrict__ s, const float* __restrict__ h,
    float* __restrict__ out)
{
    long long gid = (long long)blockIdx.x * 256 + threadIdx.x;
    int lane = (int)(gid & 31);
    long long eidx = gid >> 5;
    if (eidx >= (long long)(E + N)) return;
    int src, dst;
    if (eidx < E) { src = ei[eidx]; dst = ei[E + eidx]; }
    else { src = dst = (int)(eidx - E); }
    int head = lane >> 3;
    float e = alpha_s[src * 4 + head] + alpha_d[dst * 4 + head];
    e = e > 0.f ? e : NEG_SLOPE * e;
    float a = __expf(e) / (s[dst * 4 + head] + EPSF);
    float4 hv = ((const float4*)(h + src * 128))[lane];
    float* op = out + dst * 128 + lane * 4;
    unsafeAtomicAdd(op + 0, hv.x * a);
    unsafeAtomicAdd(op + 1, hv.y * a);
    unsafeAtomicAdd(op + 2, hv.z * a);
    unsafeAtomicAdd(op + 3, hv.w * a);
}

// ============================================================ MLP head
// one wave per node; lanes j (0..31) x halves (k split 2x128)
__global__ __launch_bounds__(256) void mlp_kernel(
    const float* __restrict__ x3, const float* __restrict__ x0,
    const float* __restrict__ W1, const float* __restrict__ b1,
    const float* __restrict__ W2, const float* __restrict__ b2,
    float* __restrict__ out, int N)
{
    __shared__ float hc[4][256];
    const int nb = threadIdx.x >> 6;
    const int lane = threadIdx.x & 63;
    int node = blockIdx.x * 4 + nb;
    int nclamp = node < N ? node : N - 1;

    // stage hcat = [x3[node], x0[node]] into LDS
    float4 v;
    if (lane < 32) v = ((const float4*)x3)[nclamp * 32 + lane];
    else           v = ((const float4*)x0)[nclamp * 32 + (lane - 32)];
    ((float4*)hc[nb])[lane] = v;
    __syncthreads();

    const int j = lane & 31;
    const int half = lane >> 5;
    float acc = 0.f;
    const float* hrow = hc[nb] + half * 128;
    const float* wp = W1 + half * 128 * 32 + j;
#pragma unroll 8
    for (int k = 0; k < 128; ++k)
        acc += hrow[k] * wp[k * 32];
    acc += __shfl_down(acc, 32, 64);

    if (lane < 32 && node < N) {
        float r = acc + b1[j];
        r = r > 0.f ? r : 0.f;
        float p = r * W2[j];
        p += __shfl_down(p, 16, 32);
        p += __shfl_down(p, 8, 32);
        p += __shfl_down(p, 4, 32);
        p += __shfl_down(p, 2, 32);
        p += __shfl_down(p, 1, 32);
        if (j == 0) {
            float z = p + b2[0];
            out[node] = 1.f / (1.f + __expf(-z));
        }
    }
}

// ============================================================ launch
extern "C" void kernel_launch(void* const* d_in, const int* in_sizes, int n_in,
                              void* d_out, int out_size, void* d_ws, size_t ws_size,
                              hipStream_t stream)
{
    const float* x       = (const float*)d_in[0];
    const int*   ei      = (const int*)d_in[1];
    const float* W       = (const float*)d_in[2];
    const float* att_src = (const float*)d_in[3];
    const float* att_dst = (const float*)d_in[4];
    const float* b_conv  = (const float*)d_in[5];
    const float* W1      = (const float*)d_in[6];
    const float* b1      = (const float*)d_in[7];
    const float* W2      = (const float*)d_in[8];
    const float* b2      = (const float*)d_in[9];
    float* outp = (float*)d_out;

    const int N = in_sizes[0] / 128;
    const int E = in_sizes[1] / 2;
    const int L = in_sizes[2] / (128 * 128);

    float* ws = (float*)d_ws;
    float* h       = ws;                    // N*128
    float* xbuf    = h + (size_t)N * 128;   // N*128 (layer out / next in)
    float* alpha_s = xbuf + (size_t)N * 128;// N*4
    float* alpha_d = alpha_s + (size_t)N * 4;
    float* s       = alpha_d + (size_t)N * 4;

    const int Etot = E + N;

    for (int l = 0; l < L; ++l) {
        const float* xin = (l == 0) ? x : xbuf;
        const float* Wl  = W + (size_t)l * 128 * 128;
        const float* asl = att_src + (size_t)l * 128;
        const float* adl = att_dst + (size_t)l * 128;
        const float* bl  = b_conv + (size_t)l * 128;

        gemm_alpha_kernel<<<(N + 63) / 64, 256, 0, stream>>>(
            xin, Wl, asl, adl, h, alpha_s, alpha_d, N);

        init_layer_kernel<<<(N * 128 + 255) / 256, 256, 0, stream>>>(
            xbuf, s, bl, N);

        edge_denom_kernel<<<(Etot + 255) / 256, 256, 0, stream>>>(
            ei, E, N, alpha_s, alpha_d, s);

        long long agg_threads = (long long)Etot * 32;
        edge_agg_kernel<<<(unsigned)((agg_threads + 255) / 256), 256, 0, stream>>>(
            ei, E, N, alpha_s, alpha_d, s, h, xbuf);
    }

    mlp_kernel<<<(N + 3) / 4, 256, 0, stream>>>(
        xbuf, x, W1, b1, W2, b2, outp, N);
}

// Round 2
// 927.771 us; speedup vs baseline: 10.2503x; 10.2503x over previous
//
#include <hip/hip_runtime.h>

#define NEG_SLOPE 0.2f
#define EPSF 1e-16f

// ============================================================ GEMM + alpha
// x:[N,128] row-major, Wl:[128,128], att_s/att_d:[128] (=[4][32] flat)
// h:[N,128], alpha_s/alpha_d:[N,4]
__global__ __launch_bounds__(256) void gemm_alpha_kernel(
    const float* __restrict__ x, const float* __restrict__ Wl,
    const float* __restrict__ att_s, const float* __restrict__ att_d,
    float* __restrict__ h, float* __restrict__ alpha_s,
    float* __restrict__ alpha_d, int N)
{
    __shared__ float4 sW[1024];   // [32][128] floats
    __shared__ float4 sX[512];    // [64][32] floats
    const int t = threadIdx.x;
    const int c4 = t & 31;        // float4 column index (cols 4*c4..4*c4+3)
    const int r0 = t >> 5;        // 0..7
    const int rowBase = blockIdx.x * 64;

    float4 acc[8];
#pragma unroll
    for (int j = 0; j < 8; ++j) acc[j] = make_float4(0.f, 0.f, 0.f, 0.f);

    const float* sXs = (const float*)sX;
    const float4* W4 = (const float4*)Wl;
    const float4* x4 = (const float4*)x;

    for (int kb = 0; kb < 128; kb += 32) {
        __syncthreads();
#pragma unroll
        for (int i = 0; i < 4; ++i) {           // W chunk [32][128]
            int f = t + i * 256;
            int k = f >> 5, cc = f & 31;
            sW[f] = W4[(kb + k) * 32 + cc];
        }
#pragma unroll
        for (int i = 0; i < 2; ++i) {           // X chunk [64][32]
            int f = t + i * 256;
            int row = f >> 3, kc = f & 7;
            int grow = rowBase + row;
            float4 v = make_float4(0.f, 0.f, 0.f, 0.f);
            if (grow < N) v = x4[grow * 32 + (kb >> 2) + kc];
            sX[row * 8 + kc] = v;
        }
        __syncthreads();
#pragma unroll
        for (int k = 0; k < 32; ++k) {
            float4 wv = sW[k * 32 + c4];
#pragma unroll
            for (int j = 0; j < 8; ++j) {
                float xv = sXs[(r0 + 8 * j) * 32 + k];
                acc[j].x += xv * wv.x; acc[j].y += xv * wv.y;
                acc[j].z += xv * wv.z; acc[j].w += xv * wv.w;
            }
        }
    }

    const float4 as4 = ((const float4*)att_s)[c4];
    const float4 ad4 = ((const float4*)att_d)[c4];
    const int head = c4 >> 3;

#pragma unroll
    for (int j = 0; j < 8; ++j) {
        int row = rowBase + r0 + 8 * j;
        if (row >= N) continue;
        float4 a = acc[j];
        ((float4*)(h + row * 128))[c4] = a;
        float ps = a.x * as4.x + a.y * as4.y + a.z * as4.z + a.w * as4.w;
        float pd = a.x * ad4.x + a.y * ad4.y + a.z * ad4.z + a.w * ad4.w;
        ps += __shfl_down(ps, 4, 8); ps += __shfl_down(ps, 2, 8); ps += __shfl_down(ps, 1, 8);
        pd += __shfl_down(pd, 4, 8); pd += __shfl_down(pd, 2, 8); pd += __shfl_down(pd, 1, 8);
        if ((c4 & 7) == 0) {
            alpha_s[row * 4 + head] = ps;
            alpha_d[row * 4 + head] = pd;
        }
    }
}

// ============================================================ CSR build
__global__ __launch_bounds__(256) void zero_deg_kernel(int* __restrict__ deg, int N)
{
    int i = blockIdx.x * 256 + threadIdx.x;
    if (i < N) deg[i] = 0;
}

__global__ __launch_bounds__(256) void hist_kernel(
    const int* __restrict__ ei, int E, int* __restrict__ deg)
{
    int i = blockIdx.x * 256 + threadIdx.x;
    if (i < E) atomicAdd(&deg[ei[E + i]], 1);   // dst half
}

// single block, 256 threads: exclusive scan of deg -> row_start[N+1], cursor
__global__ __launch_bounds__(256) void scan_kernel(
    const int* __restrict__ deg, int* __restrict__ row_start,
    int* __restrict__ cursor, int N)
{
    __shared__ int sums[256];
    const int t = threadIdx.x;
    const int chunk = (N + 255) / 256;
    const int lo = t * chunk;
    const int hi = (lo + chunk < N) ? lo + chunk : N;
    int s = 0;
    for (int i = lo; i < hi; ++i) s += deg[i];
    sums[t] = s;
    __syncthreads();
    for (int off = 1; off < 256; off <<= 1) {
        int v = sums[t];
        int add = (t >= off) ? sums[t - off] : 0;
        __syncthreads();
        sums[t] = v + add;
        __syncthreads();
    }
    int run = (t == 0) ? 0 : sums[t - 1];
    for (int i = lo; i < hi; ++i) {
        int d = deg[i];
        row_start[i] = run;
        cursor[i] = run;
        run += d;
    }
    if (t == 255) row_start[N] = run;
}

__global__ __launch_bounds__(256) void scatter_kernel(
    const int* __restrict__ ei, int E,
    int* __restrict__ cursor, int* __restrict__ csr_src)
{
    int i = blockIdx.x * 256 + threadIdx.x;
    if (i >= E) return;
    int src = ei[i];
    int dst = ei[E + i];
    int pos = atomicAdd(&cursor[dst], 1);
    csr_src[pos] = src;
}

// ============================================================ fused softmax+aggregate (CSR)
// 32 lanes per dst node; lane c4 owns channels 4*c4..4*c4+3, head = c4>>3.
// s_ex is accumulated redundantly (identical) in all 8 lanes of a head.
__global__ __launch_bounds__(256) void agg_csr_kernel(
    const int* __restrict__ csr_src, const int* __restrict__ row_start,
    const float* __restrict__ alpha_s, const float* __restrict__ alpha_d,
    const float* __restrict__ h, const float* __restrict__ b,
    float* __restrict__ out, int N)
{
    const int g = (blockIdx.x * 256 + threadIdx.x) >> 5;   // node
    const int c4 = threadIdx.x & 31;
    if (g >= N) return;
    const int head = c4 >> 3;
    const float4* h4 = (const float4*)h;

    const float ad = alpha_d[g * 4 + head];
    // self loop
    float e = alpha_s[g * 4 + head] + ad;
    e = e > 0.f ? e : NEG_SLOPE * e;
    float ex = __expf(e);
    float4 hv = h4[g * 32 + c4];
    float4 acc = make_float4(ex * hv.x, ex * hv.y, ex * hv.z, ex * hv.w);
    float sx = ex;

    const int beg = row_start[g];
    const int end = row_start[g + 1];
    for (int k = beg; k < end; ++k) {
        int src = csr_src[k];
        float e2 = alpha_s[src * 4 + head] + ad;
        e2 = e2 > 0.f ? e2 : NEG_SLOPE * e2;
        float ex2 = __expf(e2);
        float4 hv2 = h4[src * 32 + c4];
        acc.x += ex2 * hv2.x; acc.y += ex2 * hv2.y;
        acc.z += ex2 * hv2.z; acc.w += ex2 * hv2.w;
        sx += ex2;
    }
    const float inv = 1.f / (sx + EPSF);
    const float4 bv = ((const float4*)b)[c4];
    float4 o = make_float4(bv.x + acc.x * inv, bv.y + acc.y * inv,
                           bv.z + acc.z * inv, bv.w + acc.w * inv);
    ((float4*)out)[g * 32 + c4] = o;
}

// ============================================================ MLP head
__global__ __launch_bounds__(256) void mlp_kernel(
    const float* __restrict__ x3, const float* __restrict__ x0,
    const float* __restrict__ W1, const float* __restrict__ b1,
    const float* __restrict__ W2, const float* __restrict__ b2,
    float* __restrict__ out, int N)
{
    __shared__ float hc[4][256];
    const int nb = threadIdx.x >> 6;
    const int lane = threadIdx.x & 63;
    int node = blockIdx.x * 4 + nb;
    int nclamp = node < N ? node : N - 1;

    float4 v;
    if (lane < 32) v = ((const float4*)x3)[nclamp * 32 + lane];
    else           v = ((const float4*)x0)[nclamp * 32 + (lane - 32)];
    ((float4*)hc[nb])[lane] = v;
    __syncthreads();

    const int j = lane & 31;
    const int half = lane >> 5;
    float acc = 0.f;
    const float* hrow = hc[nb] + half * 128;
    const float* wp = W1 + half * 128 * 32 + j;
#pragma unroll 8
    for (int k = 0; k < 128; ++k)
        acc += hrow[k] * wp[k * 32];
    acc += __shfl_down(acc, 32, 64);

    if (lane < 32 && node < N) {
        float r = acc + b1[j];
        r = r > 0.f ? r : 0.f;
        float p = r * W2[j];
        p += __shfl_down(p, 16, 32);
        p += __shfl_down(p, 8, 32);
        p += __shfl_down(p, 4, 32);
        p += __shfl_down(p, 2, 32);
        p += __shfl_down(p, 1, 32);
        if (j == 0) {
            float z = p + b2[0];
            out[node] = 1.f / (1.f + __expf(-z));
        }
    }
}

// ============================================================ launch
extern "C" void kernel_launch(void* const* d_in, const int* in_sizes, int n_in,
                              void* d_out, int out_size, void* d_ws, size_t ws_size,
                              hipStream_t stream)
{
    const float* x       = (const float*)d_in[0];
    const int*   ei      = (const int*)d_in[1];
    const float* W       = (const float*)d_in[2];
    const float* att_src = (const float*)d_in[3];
    const float* att_dst = (const float*)d_in[4];
    const float* b_conv  = (const float*)d_in[5];
    const float* W1      = (const float*)d_in[6];
    const float* b1      = (const float*)d_in[7];
    const float* W2      = (const float*)d_in[8];
    const float* b2      = (const float*)d_in[9];
    float* outp = (float*)d_out;

    const int N = in_sizes[0] / 128;
    const int E = in_sizes[1] / 2;
    const int L = in_sizes[2] / (128 * 128);

    float* ws = (float*)d_ws;
    float* h       = ws;                        // N*128
    float* xbuf    = h + (size_t)N * 128;       // N*128
    float* alpha_s = xbuf + (size_t)N * 128;    // N*4
    float* alpha_d = alpha_s + (size_t)N * 4;   // N*4
    int* deg       = (int*)(alpha_d + (size_t)N * 4);  // N
    int* row_start = deg + N;                   // N+1
    int* cursor    = row_start + N + 1;         // N
    int* csr_src   = cursor + N;                // E

    // ---- CSR build (graph is layer-invariant: do once per call) ----
    zero_deg_kernel<<<(N + 255) / 256, 256, 0, stream>>>(deg, N);
    hist_kernel<<<(E + 255) / 256, 256, 0, stream>>>(ei, E, deg);
    scan_kernel<<<1, 256, 0, stream>>>(deg, row_start, cursor, N);
    scatter_kernel<<<(E + 255) / 256, 256, 0, stream>>>(ei, E, cursor, csr_src);

    for (int l = 0; l < L; ++l) {
        const float* xin = (l == 0) ? x : xbuf;
        const float* Wl  = W + (size_t)l * 128 * 128;
        const float* asl = att_src + (size_t)l * 128;
        const float* adl = att_dst + (size_t)l * 128;
        const float* bl  = b_conv + (size_t)l * 128;

        gemm_alpha_kernel<<<(N + 63) / 64, 256, 0, stream>>>(
            xin, Wl, asl, adl, h, alpha_s, alpha_d, N);

        agg_csr_kernel<<<(N * 32 + 255) / 256, 256, 0, stream>>>(
            csr_src, row_start, alpha_s, alpha_d, h, bl, xbuf, N);
    }

    mlp_kernel<<<(N + 3) / 4, 256, 0, stream>>>(
        xbuf, x, W1, b1, W2, b2, outp, N);
}

// Round 3
// 663.928 us; speedup vs baseline: 14.3237x; 1.3974x over previous
//
#include <hip/hip_runtime.h>

#define NEG_SLOPE 0.2f
#define EPSF 1e-16f

typedef unsigned int uint;
typedef unsigned short ushort;

// RNE float->bf16 (finite values)
static __device__ __forceinline__ ushort f2bf(float f) {
    uint u = __float_as_uint(f);
    return (ushort)((u + 0x7FFFu + ((u >> 16) & 1u)) >> 16);
}
static __device__ __forceinline__ float bf_lo(uint p) { return __uint_as_float(p << 16); }
static __device__ __forceinline__ float bf_hi(uint p) { return __uint_as_float(p & 0xFFFF0000u); }

// ============================================================ GEMM + alpha
// x:[N,128] fp32, Wl:[128,128], att_s/att_d:[128] (=[4][32])
// h2:[N,64] uint (bf16x2 packed, RNE), alpha_s/alpha_d:[N,4] fp32
__global__ __launch_bounds__(256) void gemm_alpha_kernel(
    const float* __restrict__ x, const float* __restrict__ Wl,
    const float* __restrict__ att_s, const float* __restrict__ att_d,
    uint* __restrict__ h2, float* __restrict__ alpha_s,
    float* __restrict__ alpha_d, int N)
{
    __shared__ float4 sW[1024];   // [32][128] floats
    __shared__ float4 sX[512];    // [64][32] floats
    const int t = threadIdx.x;
    const int c4 = t & 31;        // float4 column index
    const int r0 = t >> 5;        // 0..7
    const int rowBase = blockIdx.x * 64;

    float4 acc[8];
#pragma unroll
    for (int j = 0; j < 8; ++j) acc[j] = make_float4(0.f, 0.f, 0.f, 0.f);

    const float* sXs = (const float*)sX;
    const float4* W4 = (const float4*)Wl;
    const float4* x4 = (const float4*)x;

    for (int kb = 0; kb < 128; kb += 32) {
        __syncthreads();
#pragma unroll
        for (int i = 0; i < 4; ++i) {
            int f = t + i * 256;
            int k = f >> 5, cc = f & 31;
            sW[f] = W4[(kb + k) * 32 + cc];
        }
#pragma unroll
        for (int i = 0; i < 2; ++i) {
            int f = t + i * 256;
            int row = f >> 3, kc = f & 7;
            int grow = rowBase + row;
            float4 v = make_float4(0.f, 0.f, 0.f, 0.f);
            if (grow < N) v = x4[grow * 32 + (kb >> 2) + kc];
            sX[row * 8 + kc] = v;
        }
        __syncthreads();
#pragma unroll
        for (int k = 0; k < 32; ++k) {
            float4 wv = sW[k * 32 + c4];
#pragma unroll
            for (int j = 0; j < 8; ++j) {
                float xv = sXs[(r0 + 8 * j) * 32 + k];
                acc[j].x += xv * wv.x; acc[j].y += xv * wv.y;
                acc[j].z += xv * wv.z; acc[j].w += xv * wv.w;
            }
        }
    }

    const float4 as4 = ((const float4*)att_s)[c4];
    const float4 ad4 = ((const float4*)att_d)[c4];
    const int head = c4 >> 3;

#pragma unroll
    for (int j = 0; j < 8; ++j) {
        int row = rowBase + r0 + 8 * j;
        if (row >= N) continue;
        float4 a = acc[j];
        uint2 p;
        p.x = (uint)f2bf(a.x) | ((uint)f2bf(a.y) << 16);
        p.y = (uint)f2bf(a.z) | ((uint)f2bf(a.w) << 16);
        ((uint2*)(h2 + (size_t)row * 64))[c4] = p;
        float ps = a.x * as4.x + a.y * as4.y + a.z * as4.z + a.w * as4.w;
        float pd = a.x * ad4.x + a.y * ad4.y + a.z * ad4.z + a.w * ad4.w;
        ps += __shfl_down(ps, 4, 8); ps += __shfl_down(ps, 2, 8); ps += __shfl_down(ps, 1, 8);
        pd += __shfl_down(pd, 4, 8); pd += __shfl_down(pd, 2, 8); pd += __shfl_down(pd, 1, 8);
        if ((c4 & 7) == 0) {
            alpha_s[row * 4 + head] = ps;
            alpha_d[row * 4 + head] = pd;
        }
    }
}

// ============================================================ CSR build
__global__ __launch_bounds__(256) void zero_deg_kernel(int* __restrict__ deg, int N)
{
    int i = blockIdx.x * 256 + threadIdx.x;
    if (i < N) deg[i] = 0;
}

__global__ __launch_bounds__(256) void hist_kernel(
    const int* __restrict__ ei, int E, int* __restrict__ deg)
{
    int i = blockIdx.x * 256 + threadIdx.x;
    if (i < E) atomicAdd(&deg[ei[E + i]], 1);
}

// per-block reduce of deg -> bsums[block]
__global__ __launch_bounds__(256) void scan_bsum_kernel(
    const int* __restrict__ deg, int* __restrict__ bsums, int N)
{
    __shared__ int s[256];
    int i = blockIdx.x * 256 + threadIdx.x;
    s[threadIdx.x] = (i < N) ? deg[i] : 0;
    __syncthreads();
    for (int off = 128; off > 0; off >>= 1) {
        if (threadIdx.x < off) s[threadIdx.x] += s[threadIdx.x + off];
        __syncthreads();
    }
    if (threadIdx.x == 0) bsums[blockIdx.x] = s[0];
}

// single block: exclusive-scan bsums (nb <= 256), total -> *totalp
__global__ __launch_bounds__(256) void scan_off_kernel(
    int* __restrict__ bsums, int nb, int* __restrict__ totalp)
{
    __shared__ int s[256];
    const int t = threadIdx.x;
    int v = (t < nb) ? bsums[t] : 0;
    s[t] = v;
    __syncthreads();
    for (int off = 1; off < 256; off <<= 1) {
        int x = s[t];
        int a = (t >= off) ? s[t - off] : 0;
        __syncthreads();
        s[t] = x + a;
        __syncthreads();
    }
    if (t < nb) bsums[t] = s[t] - v;       // exclusive block offset
    if (t == 255) *totalp = s[255];
}

// per-block scan + add offset -> row_start, cursor
__global__ __launch_bounds__(256) void scan_write_kernel(
    const int* __restrict__ deg, const int* __restrict__ bsums,
    int* __restrict__ row_start, int* __restrict__ cursor, int N)
{
    __shared__ int s[256];
    const int t = threadIdx.x;
    int i = blockIdx.x * 256 + t;
    int v = (i < N) ? deg[i] : 0;
    s[t] = v;
    __syncthreads();
    for (int off = 1; off < 256; off <<= 1) {
        int x = s[t];
        int a = (t >= off) ? s[t - off] : 0;
        __syncthreads();
        s[t] = x + a;
        __syncthreads();
    }
    if (i < N) {
        int ex = bsums[blockIdx.x] + s[t] - v;
        row_start[i] = ex;
        cursor[i] = ex;
    }
}

__global__ __launch_bounds__(256) void scatter_kernel(
    const int* __restrict__ ei, int E,
    int* __restrict__ cursor, int* __restrict__ csr_src)
{
    int i = blockIdx.x * 256 + threadIdx.x;
    if (i >= E) return;
    int src = ei[i];
    int dst = ei[E + i];
    int pos = atomicAdd(&cursor[dst], 1);
    csr_src[pos] = src;
}

// ============================================================ fused softmax+aggregate
// 16 lanes per dst node; lane l owns channels 8l..8l+7 (head = l>>2).
// h gathered as bf16x8 (uint4 = 16B per lane per edge).
__global__ __launch_bounds__(256) void agg_csr_kernel(
    const int* __restrict__ csr_src, const int* __restrict__ row_start,
    const float* __restrict__ alpha_s, const float* __restrict__ alpha_d,
    const uint* __restrict__ h2, const float* __restrict__ b,
    float* __restrict__ out, int N)
{
    const int g = (blockIdx.x * 256 + threadIdx.x) >> 4;   // node
    const int l = threadIdx.x & 15;
    if (g >= N) return;
    const int head = l >> 2;
    const uint4* h4 = (const uint4*)h2;   // [N][16]

    const float ad = alpha_d[g * 4 + head];

    // self loop
    float e = alpha_s[g * 4 + head] + ad;
    e = e > 0.f ? e : NEG_SLOPE * e;
    float ex = __expf(e);
    uint4 q = h4[(size_t)g * 16 + l];
    float acc0 = ex * bf_lo(q.x), acc1 = ex * bf_hi(q.x);
    float acc2 = ex * bf_lo(q.y), acc3 = ex * bf_hi(q.y);
    float acc4 = ex * bf_lo(q.z), acc5 = ex * bf_hi(q.z);
    float acc6 = ex * bf_lo(q.w), acc7 = ex * bf_hi(q.w);
    float sx = ex;

    const int beg = row_start[g];
    const int end = row_start[g + 1];
    for (int k = beg; k < end; ++k) {
        int src = csr_src[k];
        float e2 = alpha_s[src * 4 + head] + ad;
        e2 = e2 > 0.f ? e2 : NEG_SLOPE * e2;
        float ex2 = __expf(e2);
        uint4 q2 = h4[(size_t)src * 16 + l];
        acc0 += ex2 * bf_lo(q2.x); acc1 += ex2 * bf_hi(q2.x);
        acc2 += ex2 * bf_lo(q2.y); acc3 += ex2 * bf_hi(q2.y);
        acc4 += ex2 * bf_lo(q2.z); acc5 += ex2 * bf_hi(q2.z);
        acc6 += ex2 * bf_lo(q2.w); acc7 += ex2 * bf_hi(q2.w);
        sx += ex2;
    }
    const float inv = 1.f / (sx + EPSF);
    const float4 b0 = ((const float4*)b)[l * 2];
    const float4 b1 = ((const float4*)b)[l * 2 + 1];
    float4 o0 = make_float4(b0.x + acc0 * inv, b0.y + acc1 * inv,
                            b0.z + acc2 * inv, b0.w + acc3 * inv);
    float4 o1 = make_float4(b1.x + acc4 * inv, b1.y + acc5 * inv,
                            b1.z + acc6 * inv, b1.w + acc7 * inv);
    float4* op = (float4*)(out + (size_t)g * 128);
    op[l * 2] = o0;
    op[l * 2 + 1] = o1;
}

// ============================================================ MLP head
__global__ __launch_bounds__(256) void mlp_kernel(
    const float* __restrict__ x3, const float* __restrict__ x0,
    const float* __restrict__ W1, const float* __restrict__ b1,
    const float* __restrict__ W2, const float* __restrict__ b2,
    float* __restrict__ out, int N)
{
    __shared__ float hc[4][256];
    const int nb = threadIdx.x >> 6;
    const int lane = threadIdx.x & 63;
    int node = blockIdx.x * 4 + nb;
    int nclamp = node < N ? node : N - 1;

    float4 v;
    if (lane < 32) v = ((const float4*)x3)[nclamp * 32 + lane];
    else           v = ((const float4*)x0)[nclamp * 32 + (lane - 32)];
    ((float4*)hc[nb])[lane] = v;
    __syncthreads();

    const int j = lane & 31;
    const int half = lane >> 5;
    float acc = 0.f;
    const float* hrow = hc[nb] + half * 128;
    const float* wp = W1 + half * 128 * 32 + j;
#pragma unroll 8
    for (int k = 0; k < 128; ++k)
        acc += hrow[k] * wp[k * 32];
    acc += __shfl_down(acc, 32, 64);

    if (lane < 32 && node < N) {
        float r = acc + b1[j];
        r = r > 0.f ? r : 0.f;
        float p = r * W2[j];
        p += __shfl_down(p, 16, 32);
        p += __shfl_down(p, 8, 32);
        p += __shfl_down(p, 4, 32);
        p += __shfl_down(p, 2, 32);
        p += __shfl_down(p, 1, 32);
        if (j == 0) {
            float z = p + b2[0];
            out[node] = 1.f / (1.f + __expf(-z));
        }
    }
}

// ============================================================ launch
extern "C" void kernel_launch(void* const* d_in, const int* in_sizes, int n_in,
                              void* d_out, int out_size, void* d_ws, size_t ws_size,
                              hipStream_t stream)
{
    const float* x       = (const float*)d_in[0];
    const int*   ei      = (const int*)d_in[1];
    const float* W       = (const float*)d_in[2];
    const float* att_src = (const float*)d_in[3];
    const float* att_dst = (const float*)d_in[4];
    const float* b_conv  = (const float*)d_in[5];
    const float* W1      = (const float*)d_in[6];
    const float* b1      = (const float*)d_in[7];
    const float* W2      = (const float*)d_in[8];
    const float* b2      = (const float*)d_in[9];
    float* outp = (float*)d_out;

    const int N = in_sizes[0] / 128;
    const int E = in_sizes[1] / 2;
    const int L = in_sizes[2] / (128 * 128);

    char* ws = (char*)d_ws;
    uint*  h2      = (uint*)ws;                           // N*64 uints (bf16 h)
    float* xbuf    = (float*)(h2 + (size_t)N * 64);       // N*128
    float* alpha_s = xbuf + (size_t)N * 128;              // N*4
    float* alpha_d = alpha_s + (size_t)N * 4;             // N*4
    int* deg       = (int*)(alpha_d + (size_t)N * 4);     // N
    int* row_start = deg + N;                             // N+1
    int* cursor    = row_start + N + 1;                   // N
    int* bsums     = cursor + N;                          // 256
    int* csr_src   = bsums + 256;                         // E

    const int nbN = (N + 255) / 256;   // <= 256 required (N <= 65536)

    // ---- CSR build (graph is layer-invariant) ----
    zero_deg_kernel<<<nbN, 256, 0, stream>>>(deg, N);
    hist_kernel<<<(E + 255) / 256, 256, 0, stream>>>(ei, E, deg);
    scan_bsum_kernel<<<nbN, 256, 0, stream>>>(deg, bsums, N);
    scan_off_kernel<<<1, 256, 0, stream>>>(bsums, nbN, row_start + N);
    scan_write_kernel<<<nbN, 256, 0, stream>>>(deg, bsums, row_start, cursor, N);
    scatter_kernel<<<(E + 255) / 256, 256, 0, stream>>>(ei, E, cursor, csr_src);

    for (int l = 0; l < L; ++l) {
        const float* xin = (l == 0) ? x : xbuf;
        const float* Wl  = W + (size_t)l * 128 * 128;
        const float* asl = att_src + (size_t)l * 128;
        const float* adl = att_dst + (size_t)l * 128;
        const float* bl  = b_conv + (size_t)l * 128;

        gemm_alpha_kernel<<<(N + 63) / 64, 256, 0, stream>>>(
            xin, Wl, asl, adl, h2, alpha_s, alpha_d, N);

        agg_csr_kernel<<<(N * 16 + 255) / 256, 256, 0, stream>>>(
            csr_src, row_start, alpha_s, alpha_d, h2, bl, xbuf, N);
    }

    mlp_kernel<<<(N + 3) / 4, 256, 0, stream>>>(
        xbuf, x, W1, b1, W2, b2, outp, N);
}

// Round 4
// 505.819 us; speedup vs baseline: 18.8010x; 1.3126x over previous
//
#include <hip/hip_runtime.h>

#define NEG_SLOPE 0.2f
#define EPSF 1e-16f

typedef unsigned int uint;
typedef unsigned short ushort;
typedef __attribute__((ext_vector_type(8))) short short8;   // 8 bf16 (4 VGPRs)
typedef __attribute__((ext_vector_type(4))) float floatx4;  // MFMA acc

// RNE float->bf16
static __device__ __forceinline__ ushort f2bf(float f) {
    uint u = __float_as_uint(f);
    return (ushort)((u + 0x7FFFu + ((u >> 16) & 1u)) >> 16);
}
static __device__ __forceinline__ uint pack2(float a, float b) {
    return (uint)f2bf(a) | ((uint)f2bf(b) << 16);
}
static __device__ __forceinline__ float bf_lo(uint p) { return __uint_as_float(p << 16); }
static __device__ __forceinline__ float bf_hi(uint p) { return __uint_as_float(p & 0xFFFF0000u); }
static __device__ __forceinline__ short8 u2s8(uint4 v) {
    union { uint4 u; short8 s; } c; c.u = v; return c.s;
}

// ============================================================ GEMM + alpha (MFMA)
// h = x@W (64 rows/block, 128 cols), bf16 inputs via LDS staging, fp32 acc.
// Frag layouts (m89-verified): A[m=lane&15][k=quad*8+j]; B[k][n=lane&15];
// D: col=lane&15, row=quad*4+reg.
// LDS: sW_perm[chunk(16)][col(128)] uint4 (W[8c+j][col]); sX_perm[chunk(16)][row(64), pad 65]
// then reused as D fp32 [64][129].
#define GA_LDS_BYTES ((2048 + 1040) * 16)   // 49408 > 64*129*4 = 33024
__global__ __launch_bounds__(256) void gemm_alpha_kernel(
    const float* __restrict__ x, const float* __restrict__ Wl,
    const float* __restrict__ att_s, const float* __restrict__ att_d,
    uint* __restrict__ h2, float* __restrict__ alpha_s,
    float* __restrict__ alpha_d, int N)
{
    __shared__ __align__(16) char smraw[GA_LDS_BYTES];
    uint4* sW = (uint4*)smraw;            // 2048 slots
    uint4* sX = sW + 2048;                // 16 chunks * 65 slots
    float* sD = (float*)smraw;            // [64][129]

    const int t = threadIdx.x;
    const int rowBase = blockIdx.x * 64;
    const float4* x4 = (const float4*)x;

    // stage W: slot = chunk*128 + col holds W[8*chunk + j][col], j=0..7
#pragma unroll
    for (int i = 0; i < 8; ++i) {
        int slot = t + i * 256;
        int chunk = slot >> 7, col = slot & 127;
        const float* wp = Wl + (chunk * 8) * 128 + col;
        uint4 pk;
        pk.x = pack2(wp[0],   wp[128]);
        pk.y = pack2(wp[256], wp[384]);
        pk.z = pack2(wp[512], wp[640]);
        pk.w = pack2(wp[768], wp[896]);
        sW[slot] = pk;
    }
    // stage x: [64 rows][128 k] fp32 -> bf16 perm
#pragma unroll
    for (int i = 0; i < 8; ++i) {
        int f = t + i * 256;
        int row = f >> 5, c4 = f & 31;
        float4 v = make_float4(0.f, 0.f, 0.f, 0.f);
        if (rowBase + row < N) v = x4[(size_t)(rowBase + row) * 32 + c4];
        uint2 p; p.x = pack2(v.x, v.y); p.y = pack2(v.z, v.w);
        ((uint2*)&sX[(c4 >> 1) * 65 + row])[c4 & 1] = p;
    }
    __syncthreads();

    const int w = t >> 6, lane = t & 63, q = lane >> 4, l15 = lane & 15;
    short8 a[4];
#pragma unroll
    for (int s = 0; s < 4; ++s)
        a[s] = u2s8(sX[(4 * s + q) * 65 + 16 * w + l15]);

    floatx4 acc[8];
#pragma unroll
    for (int ct = 0; ct < 8; ++ct) acc[ct] = (floatx4){0.f, 0.f, 0.f, 0.f};
#pragma unroll
    for (int ct = 0; ct < 8; ++ct) {
#pragma unroll
        for (int s = 0; s < 4; ++s) {
            short8 b = u2s8(sW[(4 * s + q) * 128 + 16 * ct + l15]);
            acc[ct] = __builtin_amdgcn_mfma_f32_16x16x32_bf16(a[s], b, acc[ct], 0, 0, 0);
        }
    }
    __syncthreads();   // done reading staging LDS

    // D -> LDS fp32 [64][129]
#pragma unroll
    for (int ct = 0; ct < 8; ++ct) {
#pragma unroll
        for (int r = 0; r < 4; ++r)
            sD[(16 * w + 4 * q + r) * 129 + 16 * ct + l15] = acc[ct][r];
    }
    __syncthreads();

    // h2 (packed bf16x2, uint4 = 8 ch) coalesced store
#pragma unroll
    for (int i = 0; i < 4; ++i) {
        int slot = t + i * 256;           // 1024 = 64 rows * 16
        int row = slot >> 4, c8 = slot & 15;
        if (rowBase + row < N) {
            const float* dp = &sD[row * 129 + c8 * 8];
            uint4 o;
            o.x = pack2(dp[0], dp[1]); o.y = pack2(dp[2], dp[3]);
            o.z = pack2(dp[4], dp[5]); o.w = pack2(dp[6], dp[7]);
            ((uint4*)h2)[(size_t)(rowBase + row) * 16 + c8] = o;
        }
    }
    // alphas: thread -> (row = t&63, head = t>>6), fp32 dot over 32 ch
    {
        int row = t & 63, head = t >> 6;
        if (rowBase + row < N) {
            const float* dp = &sD[row * 129 + head * 32];
            const float* asp = att_s + head * 32;
            const float* adp = att_d + head * 32;
            float ps = 0.f, pd = 0.f;
#pragma unroll
            for (int c = 0; c < 32; ++c) { float v = dp[c]; ps += v * asp[c]; pd += v * adp[c]; }
            alpha_s[(size_t)(rowBase + row) * 4 + head] = ps;
            alpha_d[(size_t)(rowBase + row) * 4 + head] = pd;
        }
    }
}

// ============================================================ CSR build
__global__ __launch_bounds__(256) void zero_deg_kernel(int* __restrict__ deg, int N)
{
    int i = blockIdx.x * 256 + threadIdx.x;
    if (i < N) deg[i] = 0;
}

__global__ __launch_bounds__(256) void hist_kernel(
    const int* __restrict__ ei, int E, int* __restrict__ deg)
{
    int i = blockIdx.x * 256 + threadIdx.x;
    if (i < E) atomicAdd(&deg[ei[E + i]], 1);
}

__global__ __launch_bounds__(256) void scan_bsum_kernel(
    const int* __restrict__ deg, int* __restrict__ bsums, int N)
{
    __shared__ int s[256];
    int i = blockIdx.x * 256 + threadIdx.x;
    s[threadIdx.x] = (i < N) ? deg[i] : 0;
    __syncthreads();
    for (int off = 128; off > 0; off >>= 1) {
        if (threadIdx.x < off) s[threadIdx.x] += s[threadIdx.x + off];
        __syncthreads();
    }
    if (threadIdx.x == 0) bsums[blockIdx.x] = s[0];
}

__global__ __launch_bounds__(256) void scan_off_kernel(
    int* __restrict__ bsums, int nb, int* __restrict__ totalp)
{
    __shared__ int s[256];
    const int t = threadIdx.x;
    int v = (t < nb) ? bsums[t] : 0;
    s[t] = v;
    __syncthreads();
    for (int off = 1; off < 256; off <<= 1) {
        int x = s[t];
        int a = (t >= off) ? s[t - off] : 0;
        __syncthreads();
        s[t] = x + a;
        __syncthreads();
    }
    if (t < nb) bsums[t] = s[t] - v;
    if (t == 255) *totalp = s[255];
}

__global__ __launch_bounds__(256) void scan_write_kernel(
    const int* __restrict__ deg, const int* __restrict__ bsums,
    int* __restrict__ row_start, int* __restrict__ cursor, int N)
{
    __shared__ int s[256];
    const int t = threadIdx.x;
    int i = blockIdx.x * 256 + t;
    int v = (i < N) ? deg[i] : 0;
    s[t] = v;
    __syncthreads();
    for (int off = 1; off < 256; off <<= 1) {
        int x = s[t];
        int a = (t >= off) ? s[t - off] : 0;
        __syncthreads();
        s[t] = x + a;
        __syncthreads();
    }
    if (i < N) {
        int ex = bsums[blockIdx.x] + s[t] - v;
        row_start[i] = ex;
        cursor[i] = ex;
    }
}

// windowed scatter: 8 edges/thread in registers, 8 dst-window passes so the
// csr_src write window (~N/8 segment) stays L2-resident (cuts partial-line
// write-back amplification across XCDs).
__global__ __launch_bounds__(256) void scatter_kernel(
    const int* __restrict__ ei, int E, int N,
    int* __restrict__ cursor, int* __restrict__ csr_src)
{
    const int base = (blockIdx.x * 256 + threadIdx.x) * 8;
    int srcs[8], dsts[8];
    if (base + 8 <= E && (E & 3) == 0) {
        int4 a0 = ((const int4*)(ei + base))[0];
        int4 a1 = ((const int4*)(ei + base))[1];
        int4 b0 = ((const int4*)(ei + E + base))[0];
        int4 b1 = ((const int4*)(ei + E + base))[1];
        srcs[0]=a0.x; srcs[1]=a0.y; srcs[2]=a0.z; srcs[3]=a0.w;
        srcs[4]=a1.x; srcs[5]=a1.y; srcs[6]=a1.z; srcs[7]=a1.w;
        dsts[0]=b0.x; dsts[1]=b0.y; dsts[2]=b0.z; dsts[3]=b0.w;
        dsts[4]=b1.x; dsts[5]=b1.y; dsts[6]=b1.z; dsts[7]=b1.w;
    } else {
#pragma unroll
        for (int j = 0; j < 8; ++j) {
            int idx = base + j;
            if (idx < E) { srcs[j] = ei[idx]; dsts[j] = ei[E + idx]; }
            else { srcs[j] = 0; dsts[j] = -1; }
        }
    }
    const int Wsz = (N + 7) >> 3;
    for (int p = 0; p < 8; ++p) {
        int lo = p * Wsz, hi = lo + Wsz;
#pragma unroll
        for (int j = 0; j < 8; ++j) {
            if (dsts[j] >= lo && dsts[j] < hi) {
                int pos = atomicAdd(&cursor[dsts[j]], 1);
                csr_src[pos] = srcs[j];
            }
        }
    }
}

// ============================================================ fused softmax+aggregate
// 16 lanes per dst node; lane l owns channels 8l..8l+7 (head = l>>2); 2-wide unroll.
__global__ __launch_bounds__(256) void agg_csr_kernel(
    const int* __restrict__ csr_src, const int* __restrict__ row_start,
    const float* __restrict__ alpha_s, const float* __restrict__ alpha_d,
    const uint* __restrict__ h2, const float* __restrict__ b,
    float* __restrict__ out, int N)
{
    const int g = (blockIdx.x * 256 + threadIdx.x) >> 4;
    const int l = threadIdx.x & 15;
    if (g >= N) return;
    const int head = l >> 2;
    const uint4* h4 = (const uint4*)h2;

    const float ad = alpha_d[g * 4 + head];

    // self loop
    float e = alpha_s[g * 4 + head] + ad;
    e = e > 0.f ? e : NEG_SLOPE * e;
    float ex = __expf(e);
    uint4 q = h4[(size_t)g * 16 + l];
    float a0 = ex * bf_lo(q.x), a1 = ex * bf_hi(q.x);
    float a2 = ex * bf_lo(q.y), a3 = ex * bf_hi(q.y);
    float a4 = ex * bf_lo(q.z), a5 = ex * bf_hi(q.z);
    float a6 = ex * bf_lo(q.w), a7 = ex * bf_hi(q.w);
    float sx = ex;

    const int beg = row_start[g];
    const int end = row_start[g + 1];
    int k = beg;
    for (; k + 2 <= end; k += 2) {
        int s0 = csr_src[k], s1 = csr_src[k + 1];
        float e0 = alpha_s[s0 * 4 + head] + ad;
        float e1 = alpha_s[s1 * 4 + head] + ad;
        uint4 q0 = h4[(size_t)s0 * 16 + l];
        uint4 q1 = h4[(size_t)s1 * 16 + l];
        e0 = e0 > 0.f ? e0 : NEG_SLOPE * e0;
        e1 = e1 > 0.f ? e1 : NEG_SLOPE * e1;
        float x0 = __expf(e0), x1 = __expf(e1);
        a0 += x0 * bf_lo(q0.x) + x1 * bf_lo(q1.x);
        a1 += x0 * bf_hi(q0.x) + x1 * bf_hi(q1.x);
        a2 += x0 * bf_lo(q0.y) + x1 * bf_lo(q1.y);
        a3 += x0 * bf_hi(q0.y) + x1 * bf_hi(q1.y);
        a4 += x0 * bf_lo(q0.z) + x1 * bf_lo(q1.z);
        a5 += x0 * bf_hi(q0.z) + x1 * bf_hi(q1.z);
        a6 += x0 * bf_lo(q0.w) + x1 * bf_lo(q1.w);
        a7 += x0 * bf_hi(q0.w) + x1 * bf_hi(q1.w);
        sx += x0 + x1;
    }
    if (k < end) {
        int s0 = csr_src[k];
        float e0 = alpha_s[s0 * 4 + head] + ad;
        uint4 q0 = h4[(size_t)s0 * 16 + l];
        e0 = e0 > 0.f ? e0 : NEG_SLOPE * e0;
        float x0 = __expf(e0);
        a0 += x0 * bf_lo(q0.x); a1 += x0 * bf_hi(q0.x);
        a2 += x0 * bf_lo(q0.y); a3 += x0 * bf_hi(q0.y);
        a4 += x0 * bf_lo(q0.z); a5 += x0 * bf_hi(q0.z);
        a6 += x0 * bf_lo(q0.w); a7 += x0 * bf_hi(q0.w);
        sx += x0;
    }
    const float inv = 1.f / (sx + EPSF);
    const float4 b0 = ((const float4*)b)[l * 2];
    const float4 b1 = ((const float4*)b)[l * 2 + 1];
    float4 o0 = make_float4(b0.x + a0 * inv, b0.y + a1 * inv,
                            b0.z + a2 * inv, b0.w + a3 * inv);
    float4 o1 = make_float4(b1.x + a4 * inv, b1.y + a5 * inv,
                            b1.z + a6 * inv, b1.w + a7 * inv);
    float4* op = (float4*)(out + (size_t)g * 128);
    op[l * 2] = o0;
    op[l * 2 + 1] = o1;
}

// ============================================================ MLP head (MFMA)
// hcat[64x256] (x3|x0) @ W1[256x32] -> relu -> *W2 -> sigmoid
__global__ __launch_bounds__(256) void mlp_kernel(
    const float* __restrict__ x3, const float* __restrict__ x0,
    const float* __restrict__ W1, const float* __restrict__ b1,
    const float* __restrict__ W2, const float* __restrict__ b2,
    float* __restrict__ out, int N)
{
    __shared__ __align__(16) uint4 sA[32 * 65];  // chunk(32) x row(64, pad 65)
    __shared__ __align__(16) uint4 sB[32 * 32];  // chunk(32) x col(32)
    const int t = threadIdx.x;
    const int rowBase = blockIdx.x * 64;

    // stage A = [x3 | x0] rows, bf16 perm
#pragma unroll
    for (int i = 0; i < 16; ++i) {
        int f = t + i * 256;                 // 0..4095
        int row = f >> 6, c4 = f & 63;       // k = 4*c4
        float4 v = make_float4(0.f, 0.f, 0.f, 0.f);
        int grow = rowBase + row;
        if (grow < N)
            v = (c4 < 32) ? ((const float4*)x3)[(size_t)grow * 32 + c4]
                          : ((const float4*)x0)[(size_t)grow * 32 + (c4 - 32)];
        uint2 p; p.x = pack2(v.x, v.y); p.y = pack2(v.z, v.w);
        ((uint2*)&sA[(c4 >> 1) * 65 + row])[c4 & 1] = p;
    }
    // stage B = W1 [256][32]
#pragma unroll
    for (int i = 0; i < 4; ++i) {
        int slot = t + i * 256;              // 0..1023
        int chunk = slot >> 5, col = slot & 31;
        const float* wp = W1 + (chunk * 8) * 32 + col;
        uint4 pk;
        pk.x = pack2(wp[0],   wp[32]);
        pk.y = pack2(wp[64],  wp[96]);
        pk.z = pack2(wp[128], wp[160]);
        pk.w = pack2(wp[192], wp[224]);
        sB[slot] = pk;
    }
    __syncthreads();

    const int w = t >> 6, lane = t & 63, q = lane >> 4, l15 = lane & 15;
    floatx4 acc0 = (floatx4){0.f, 0.f, 0.f, 0.f};
    floatx4 acc1 = (floatx4){0.f, 0.f, 0.f, 0.f};
#pragma unroll
    for (int s = 0; s < 8; ++s) {
        short8 a = u2s8(sA[(4 * s + q) * 65 + 16 * w + l15]);
        acc0 = __builtin_amdgcn_mfma_f32_16x16x32_bf16(a, u2s8(sB[(4 * s + q) * 32 + l15]), acc0, 0, 0, 0);
        acc1 = __builtin_amdgcn_mfma_f32_16x16x32_bf16(a, u2s8(sB[(4 * s + q) * 32 + 16 + l15]), acc1, 0, 0, 0);
    }
    const float b1a = b1[l15], b1b = b1[16 + l15];
    const float w2a = W2[l15], w2b = W2[16 + l15];
    const float b2v = b2[0];
#pragma unroll
    for (int r = 0; r < 4; ++r) {
        int row = rowBase + 16 * w + 4 * q + r;
        float v0 = acc0[r] + b1a; v0 = v0 > 0.f ? v0 : 0.f;
        float v1 = acc1[r] + b1b; v1 = v1 > 0.f ? v1 : 0.f;
        float p = v0 * w2a + v1 * w2b;
        p += __shfl_xor(p, 1);
        p += __shfl_xor(p, 2);
        p += __shfl_xor(p, 4);
        p += __shfl_xor(p, 8);
        if (l15 == 0 && row < N)
            out[row] = 1.f / (1.f + __expf(-(p + b2v)));
    }
}

// ============================================================ launch
extern "C" void kernel_launch(void* const* d_in, const int* in_sizes, int n_in,
                              void* d_out, int out_size, void* d_ws, size_t ws_size,
                              hipStream_t stream)
{
    const float* x       = (const float*)d_in[0];
    const int*   ei      = (const int*)d_in[1];
    const float* W       = (const float*)d_in[2];
    const float* att_src = (const float*)d_in[3];
    const float* att_dst = (const float*)d_in[4];
    const float* b_conv  = (const float*)d_in[5];
    const float* W1      = (const float*)d_in[6];
    const float* b1      = (const float*)d_in[7];
    const float* W2      = (const float*)d_in[8];
    const float* b2      = (const float*)d_in[9];
    float* outp = (float*)d_out;

    const int N = in_sizes[0] / 128;
    const int E = in_sizes[1] / 2;
    const int L = in_sizes[2] / (128 * 128);

    char* ws = (char*)d_ws;
    uint*  h2      = (uint*)ws;                           // N*64 uints (bf16 h)
    float* xbuf    = (float*)(h2 + (size_t)N * 64);       // N*128
    float* alpha_s = xbuf + (size_t)N * 128;              // N*4
    float* alpha_d = alpha_s + (size_t)N * 4;             // N*4
    int* deg       = (int*)(alpha_d + (size_t)N * 4);     // N
    int* row_start = deg + N;                             // N+1
    int* cursor    = row_start + N + 1;                   // N
    int* bsums     = cursor + N;                          // 256
    int* csr_src   = bsums + 256;                         // E

    const int nbN = (N + 255) / 256;

    // ---- CSR build (graph is layer-invariant) ----
    zero_deg_kernel<<<nbN, 256, 0, stream>>>(deg, N);
    hist_kernel<<<(E + 255) / 256, 256, 0, stream>>>(ei, E, deg);
    scan_bsum_kernel<<<nbN, 256, 0, stream>>>(deg, bsums, N);
    scan_off_kernel<<<1, 256, 0, stream>>>(bsums, nbN, row_start + N);
    scan_write_kernel<<<nbN, 256, 0, stream>>>(deg, bsums, row_start, cursor, N);
    scatter_kernel<<<(E + 2047) / 2048, 256, 0, stream>>>(ei, E, N, cursor, csr_src);

    for (int l = 0; l < L; ++l) {
        const float* xin = (l == 0) ? x : xbuf;
        const float* Wl  = W + (size_t)l * 128 * 128;
        const float* asl = att_src + (size_t)l * 128;
        const float* adl = att_dst + (size_t)l * 128;
        const float* bl  = b_conv + (size_t)l * 128;

        gemm_alpha_kernel<<<(N + 63) / 64, 256, 0, stream>>>(
            xin, Wl, asl, adl, h2, alpha_s, alpha_d, N);

        agg_csr_kernel<<<(N * 16 + 255) / 256, 256, 0, stream>>>(
            csr_src, row_start, alpha_s, alpha_d, h2, bl, xbuf, N);
    }

    mlp_kernel<<<(N + 63) / 64, 256, 0, stream>>>(
        xbuf, x, W1, b1, W2, b2, outp, N);
}

// Round 5
// 403.963 us; speedup vs baseline: 23.5416x; 1.2521x over previous
//
#include <hip/hip_runtime.h>

#define NEG_SLOPE 0.2f
#define EPSF 1e-16f

typedef unsigned int uint;
typedef unsigned short ushort;
typedef __attribute__((ext_vector_type(8))) short short8;   // 8 bf16 (4 VGPRs)
typedef __attribute__((ext_vector_type(4))) float floatx4;  // MFMA acc

// RNE float->bf16
static __device__ __forceinline__ ushort f2bf(float f) {
    uint u = __float_as_uint(f);
    return (ushort)((u + 0x7FFFu + ((u >> 16) & 1u)) >> 16);
}
static __device__ __forceinline__ uint pack2(float a, float b) {
    return (uint)f2bf(a) | ((uint)f2bf(b) << 16);
}
static __device__ __forceinline__ float bf_lo(uint p) { return __uint_as_float(p << 16); }
static __device__ __forceinline__ float bf_hi(uint p) { return __uint_as_float(p & 0xFFFF0000u); }
static __device__ __forceinline__ short8 u2s8(uint4 v) {
    union { uint4 u; short8 s; } c; c.u = v; return c.s;
}

// ============================================================ GEMM + alpha (MFMA)
#define GA_LDS_BYTES ((2048 + 1040) * 16)
__global__ __launch_bounds__(256) void gemm_alpha_kernel(
    const float* __restrict__ x, const float* __restrict__ Wl,
    const float* __restrict__ att_s, const float* __restrict__ att_d,
    uint* __restrict__ h2, float* __restrict__ alpha_s,
    float* __restrict__ alpha_d, int N)
{
    __shared__ __align__(16) char smraw[GA_LDS_BYTES];
    uint4* sW = (uint4*)smraw;            // 2048 slots
    uint4* sX = sW + 2048;                // 16 chunks * 65 slots
    float* sD = (float*)smraw;            // [64][129]

    const int t = threadIdx.x;
    const int rowBase = blockIdx.x * 64;
    const float4* x4 = (const float4*)x;

#pragma unroll
    for (int i = 0; i < 8; ++i) {
        int slot = t + i * 256;
        int chunk = slot >> 7, col = slot & 127;
        const float* wp = Wl + (chunk * 8) * 128 + col;
        uint4 pk;
        pk.x = pack2(wp[0],   wp[128]);
        pk.y = pack2(wp[256], wp[384]);
        pk.z = pack2(wp[512], wp[640]);
        pk.w = pack2(wp[768], wp[896]);
        sW[slot] = pk;
    }
#pragma unroll
    for (int i = 0; i < 8; ++i) {
        int f = t + i * 256;
        int row = f >> 5, c4 = f & 31;
        float4 v = make_float4(0.f, 0.f, 0.f, 0.f);
        if (rowBase + row < N) v = x4[(size_t)(rowBase + row) * 32 + c4];
        uint2 p; p.x = pack2(v.x, v.y); p.y = pack2(v.z, v.w);
        ((uint2*)&sX[(c4 >> 1) * 65 + row])[c4 & 1] = p;
    }
    __syncthreads();

    const int w = t >> 6, lane = t & 63, q = lane >> 4, l15 = lane & 15;
    short8 a[4];
#pragma unroll
    for (int s = 0; s < 4; ++s)
        a[s] = u2s8(sX[(4 * s + q) * 65 + 16 * w + l15]);

    floatx4 acc[8];
#pragma unroll
    for (int ct = 0; ct < 8; ++ct) acc[ct] = (floatx4){0.f, 0.f, 0.f, 0.f};
#pragma unroll
    for (int ct = 0; ct < 8; ++ct) {
#pragma unroll
        for (int s = 0; s < 4; ++s) {
            short8 b = u2s8(sW[(4 * s + q) * 128 + 16 * ct + l15]);
            acc[ct] = __builtin_amdgcn_mfma_f32_16x16x32_bf16(a[s], b, acc[ct], 0, 0, 0);
        }
    }
    __syncthreads();

#pragma unroll
    for (int ct = 0; ct < 8; ++ct) {
#pragma unroll
        for (int r = 0; r < 4; ++r)
            sD[(16 * w + 4 * q + r) * 129 + 16 * ct + l15] = acc[ct][r];
    }
    __syncthreads();

#pragma unroll
    for (int i = 0; i < 4; ++i) {
        int slot = t + i * 256;
        int row = slot >> 4, c8 = slot & 15;
        if (rowBase + row < N) {
            const float* dp = &sD[row * 129 + c8 * 8];
            uint4 o;
            o.x = pack2(dp[0], dp[1]); o.y = pack2(dp[2], dp[3]);
            o.z = pack2(dp[4], dp[5]); o.w = pack2(dp[6], dp[7]);
            ((uint4*)h2)[(size_t)(rowBase + row) * 16 + c8] = o;
        }
    }
    {
        int row = t & 63, head = t >> 6;
        if (rowBase + row < N) {
            const float* dp = &sD[row * 129 + head * 32];
            const float* asp = att_s + head * 32;
            const float* adp = att_d + head * 32;
            float ps = 0.f, pd = 0.f;
#pragma unroll
            for (int c = 0; c < 32; ++c) { float v = dp[c]; ps += v * asp[c]; pd += v * adp[c]; }
            alpha_s[(size_t)(rowBase + row) * 4 + head] = ps;
            alpha_d[(size_t)(rowBase + row) * 4 + head] = pd;
        }
    }
}

// ============================================================ CSR build: 2-level counting sort
// Bucket = 256 consecutive dst nodes. NB = ceil(N/256) <= 256.

__global__ __launch_bounds__(256) void zero256_kernel(int* __restrict__ p)
{
    p[threadIdx.x] = 0;
}

// S1: per-block LDS histogram of dst>>8, one global atomic per bucket
__global__ __launch_bounds__(256) void bucket_count_kernel(
    const int* __restrict__ ei, int E, int NB, int* __restrict__ bucket_count)
{
    __shared__ int cnt[256];
    cnt[threadIdx.x] = 0;
    __syncthreads();
    const int base = blockIdx.x * 2048 + threadIdx.x;
#pragma unroll
    for (int j = 0; j < 8; ++j) {
        int idx = base + j * 256;
        if (idx < E) atomicAdd(&cnt[ei[E + idx] >> 8], 1);
    }
    __syncthreads();
    int c = cnt[threadIdx.x];
    if (threadIdx.x < NB && c) atomicAdd(&bucket_count[threadIdx.x], c);
}

// S2: single block scan -> bucket_base[NB+1], bucket_cursor; row_start[N]=E
__global__ __launch_bounds__(256) void bucket_scan_kernel(
    const int* __restrict__ bucket_count, int NB,
    int* __restrict__ bucket_base, int* __restrict__ bucket_cursor,
    int* __restrict__ row_start, int N)
{
    __shared__ int s[256];
    const int t = threadIdx.x;
    int v = (t < NB) ? bucket_count[t] : 0;
    s[t] = v;
    __syncthreads();
    for (int off = 1; off < 256; off <<= 1) {
        int x = s[t];
        int a = (t >= off) ? s[t - off] : 0;
        __syncthreads();
        s[t] = x + a;
        __syncthreads();
    }
    int ex = s[t] - v;
    if (t < NB) { bucket_base[t] = ex; bucket_cursor[t] = ex; }
    if (t == 255) { bucket_base[NB] = s[255]; row_start[N] = s[255]; }
}

// S3: multisplit distribute. Packed entry: src (bits 0..15) | local_dst (bits 16..23)
__global__ __launch_bounds__(256) void distribute_kernel(
    const int* __restrict__ ei, int E, int NB,
    int* __restrict__ bucket_cursor, uint* __restrict__ bdata)
{
    __shared__ int cnt[256];
    __shared__ int bbase[256];
    cnt[threadIdx.x] = 0;
    __syncthreads();
    const int base = blockIdx.x * 2048 + threadIdx.x;
    int srcs[8], dsts[8], rank[8];
#pragma unroll
    for (int j = 0; j < 8; ++j) {
        int idx = base + j * 256;
        if (idx < E) {
            srcs[j] = ei[idx];
            dsts[j] = ei[E + idx];
            rank[j] = atomicAdd(&cnt[dsts[j] >> 8], 1);
        } else dsts[j] = -1;
    }
    __syncthreads();
    {
        int c = cnt[threadIdx.x];
        bbase[threadIdx.x] = (threadIdx.x < NB && c) ? atomicAdd(&bucket_cursor[threadIdx.x], c) : 0;
    }
    __syncthreads();
#pragma unroll
    for (int j = 0; j < 8; ++j) {
        if (dsts[j] >= 0) {
            int b = dsts[j] >> 8;
            bdata[bbase[b] + rank[j]] = (uint)srcs[j] | ((uint)(dsts[j] & 255) << 16);
        }
    }
}

// S4: one block per bucket: local hist -> scan -> row_start (coalesced) ->
// LDS scatter -> stream csr_src out as full lines (ushort entries).
#define BCAP 12800
__global__ __launch_bounds__(256) void bucket_csr_kernel(
    const uint* __restrict__ bdata, const int* __restrict__ bucket_base,
    int* __restrict__ row_start, ushort* __restrict__ csr_src, int N)
{
    __shared__ int hist[256];
    __shared__ int scn[256];
    __shared__ int cur[256];
    __shared__ ushort buf[BCAP];
    const int b = blockIdx.x;
    const int t = threadIdx.x;
    const int beg = bucket_base[b];
    const int sz = bucket_base[b + 1] - beg;
    hist[t] = 0;
    __syncthreads();
    for (int i = t; i < sz; i += 256) atomicAdd(&hist[bdata[beg + i] >> 16], 1);
    __syncthreads();
    int v = hist[t];
    scn[t] = v;
    __syncthreads();
    for (int off = 1; off < 256; off <<= 1) {
        int x = scn[t];
        int a = (t >= off) ? scn[t - off] : 0;
        __syncthreads();
        scn[t] = x + a;
        __syncthreads();
    }
    int ex = scn[t] - v;
    cur[t] = ex;
    int node = b * 256 + t;
    if (node < N) row_start[node] = beg + ex;
    __syncthreads();
    if (sz <= BCAP) {
        for (int i = t; i < sz; i += 256) {
            uint d = bdata[beg + i];
            int pos = atomicAdd(&cur[d >> 16], 1);
            buf[pos] = (ushort)(d & 0xFFFFu);
        }
        __syncthreads();
        for (int i = t; i < sz; i += 256) csr_src[beg + i] = buf[i];
    } else {
        // statistically unreachable fallback (keeps correctness for any input)
        for (int i = t; i < sz; i += 256) {
            uint d = bdata[beg + i];
            int pos = atomicAdd(&cur[d >> 16], 1);
            csr_src[beg + pos] = (ushort)(d & 0xFFFFu);
        }
    }
}

// ============================================================ fused softmax+aggregate
// 16 lanes per dst node; lane l owns channels 8l..8l+7 (head = l>>2); 2-wide unroll.
__global__ __launch_bounds__(256) void agg_csr_kernel(
    const ushort* __restrict__ csr_src, const int* __restrict__ row_start,
    const float* __restrict__ alpha_s, const float* __restrict__ alpha_d,
    const uint* __restrict__ h2, const float* __restrict__ b,
    float* __restrict__ out, int N)
{
    const int g = (blockIdx.x * 256 + threadIdx.x) >> 4;
    const int l = threadIdx.x & 15;
    if (g >= N) return;
    const int head = l >> 2;
    const uint4* h4 = (const uint4*)h2;

    const float ad = alpha_d[g * 4 + head];

    // self loop
    float e = alpha_s[g * 4 + head] + ad;
    e = e > 0.f ? e : NEG_SLOPE * e;
    float ex = __expf(e);
    uint4 q = h4[(size_t)g * 16 + l];
    float a0 = ex * bf_lo(q.x), a1 = ex * bf_hi(q.x);
    float a2 = ex * bf_lo(q.y), a3 = ex * bf_hi(q.y);
    float a4 = ex * bf_lo(q.z), a5 = ex * bf_hi(q.z);
    float a6 = ex * bf_lo(q.w), a7 = ex * bf_hi(q.w);
    float sx = ex;

    const int beg = row_start[g];
    const int end = row_start[g + 1];
    int k = beg;
    for (; k + 2 <= end; k += 2) {
        int s0 = csr_src[k], s1 = csr_src[k + 1];
        float e0 = alpha_s[s0 * 4 + head] + ad;
        float e1 = alpha_s[s1 * 4 + head] + ad;
        uint4 q0 = h4[(size_t)s0 * 16 + l];
        uint4 q1 = h4[(size_t)s1 * 16 + l];
        e0 = e0 > 0.f ? e0 : NEG_SLOPE * e0;
        e1 = e1 > 0.f ? e1 : NEG_SLOPE * e1;
        float x0 = __expf(e0), x1 = __expf(e1);
        a0 += x0 * bf_lo(q0.x) + x1 * bf_lo(q1.x);
        a1 += x0 * bf_hi(q0.x) + x1 * bf_hi(q1.x);
        a2 += x0 * bf_lo(q0.y) + x1 * bf_lo(q1.y);
        a3 += x0 * bf_hi(q0.y) + x1 * bf_hi(q1.y);
        a4 += x0 * bf_lo(q0.z) + x1 * bf_lo(q1.z);
        a5 += x0 * bf_hi(q0.z) + x1 * bf_hi(q1.z);
        a6 += x0 * bf_lo(q0.w) + x1 * bf_lo(q1.w);
        a7 += x0 * bf_hi(q0.w) + x1 * bf_hi(q1.w);
        sx += x0 + x1;
    }
    if (k < end) {
        int s0 = csr_src[k];
        float e0 = alpha_s[s0 * 4 + head] + ad;
        uint4 q0 = h4[(size_t)s0 * 16 + l];
        e0 = e0 > 0.f ? e0 : NEG_SLOPE * e0;
        float x0 = __expf(e0);
        a0 += x0 * bf_lo(q0.x); a1 += x0 * bf_hi(q0.x);
        a2 += x0 * bf_lo(q0.y); a3 += x0 * bf_hi(q0.y);
        a4 += x0 * bf_lo(q0.z); a5 += x0 * bf_hi(q0.z);
        a6 += x0 * bf_lo(q0.w); a7 += x0 * bf_hi(q0.w);
        sx += x0;
    }
    const float inv = 1.f / (sx + EPSF);
    const float4 b0 = ((const float4*)b)[l * 2];
    const float4 b1 = ((const float4*)b)[l * 2 + 1];
    float4 o0 = make_float4(b0.x + a0 * inv, b0.y + a1 * inv,
                            b0.z + a2 * inv, b0.w + a3 * inv);
    float4 o1 = make_float4(b1.x + a4 * inv, b1.y + a5 * inv,
                            b1.z + a6 * inv, b1.w + a7 * inv);
    float4* op = (float4*)(out + (size_t)g * 128);
    op[l * 2] = o0;
    op[l * 2 + 1] = o1;
}

// ============================================================ MLP head (MFMA)
__global__ __launch_bounds__(256) void mlp_kernel(
    const float* __restrict__ x3, const float* __restrict__ x0,
    const float* __restrict__ W1, const float* __restrict__ b1,
    const float* __restrict__ W2, const float* __restrict__ b2,
    float* __restrict__ out, int N)
{
    __shared__ __align__(16) uint4 sA[32 * 65];
    __shared__ __align__(16) uint4 sB[32 * 32];
    const int t = threadIdx.x;
    const int rowBase = blockIdx.x * 64;

#pragma unroll
    for (int i = 0; i < 16; ++i) {
        int f = t + i * 256;
        int row = f >> 6, c4 = f & 63;
        float4 v = make_float4(0.f, 0.f, 0.f, 0.f);
        int grow = rowBase + row;
        if (grow < N)
            v = (c4 < 32) ? ((const float4*)x3)[(size_t)grow * 32 + c4]
                          : ((const float4*)x0)[(size_t)grow * 32 + (c4 - 32)];
        uint2 p; p.x = pack2(v.x, v.y); p.y = pack2(v.z, v.w);
        ((uint2*)&sA[(c4 >> 1) * 65 + row])[c4 & 1] = p;
    }
#pragma unroll
    for (int i = 0; i < 4; ++i) {
        int slot = t + i * 256;
        int chunk = slot >> 5, col = slot & 31;
        const float* wp = W1 + (chunk * 8) * 32 + col;
        uint4 pk;
        pk.x = pack2(wp[0],   wp[32]);
        pk.y = pack2(wp[64],  wp[96]);
        pk.z = pack2(wp[128], wp[160]);
        pk.w = pack2(wp[192], wp[224]);
        sB[slot] = pk;
    }
    __syncthreads();

    const int w = t >> 6, lane = t & 63, q = lane >> 4, l15 = lane & 15;
    floatx4 acc0 = (floatx4){0.f, 0.f, 0.f, 0.f};
    floatx4 acc1 = (floatx4){0.f, 0.f, 0.f, 0.f};
#pragma unroll
    for (int s = 0; s < 8; ++s) {
        short8 a = u2s8(sA[(4 * s + q) * 65 + 16 * w + l15]);
        acc0 = __builtin_amdgcn_mfma_f32_16x16x32_bf16(a, u2s8(sB[(4 * s + q) * 32 + l15]), acc0, 0, 0, 0);
        acc1 = __builtin_amdgcn_mfma_f32_16x16x32_bf16(a, u2s8(sB[(4 * s + q) * 32 + 16 + l15]), acc1, 0, 0, 0);
    }
    const float b1a = b1[l15], b1b = b1[16 + l15];
    const float w2a = W2[l15], w2b = W2[16 + l15];
    const float b2v = b2[0];
#pragma unroll
    for (int r = 0; r < 4; ++r) {
        int row = rowBase + 16 * w + 4 * q + r;
        float v0 = acc0[r] + b1a; v0 = v0 > 0.f ? v0 : 0.f;
        float v1 = acc1[r] + b1b; v1 = v1 > 0.f ? v1 : 0.f;
        float p = v0 * w2a + v1 * w2b;
        p += __shfl_xor(p, 1);
        p += __shfl_xor(p, 2);
        p += __shfl_xor(p, 4);
        p += __shfl_xor(p, 8);
        if (l15 == 0 && row < N)
            out[row] = 1.f / (1.f + __expf(-(p + b2v)));
    }
}

// ============================================================ launch
extern "C" void kernel_launch(void* const* d_in, const int* in_sizes, int n_in,
                              void* d_out, int out_size, void* d_ws, size_t ws_size,
                              hipStream_t stream)
{
    const float* x       = (const float*)d_in[0];
    const int*   ei      = (const int*)d_in[1];
    const float* W       = (const float*)d_in[2];
    const float* att_src = (const float*)d_in[3];
    const float* att_dst = (const float*)d_in[4];
    const float* b_conv  = (const float*)d_in[5];
    const float* W1      = (const float*)d_in[6];
    const float* b1      = (const float*)d_in[7];
    const float* W2      = (const float*)d_in[8];
    const float* b2      = (const float*)d_in[9];
    float* outp = (float*)d_out;

    const int N = in_sizes[0] / 128;
    const int E = in_sizes[1] / 2;
    const int L = in_sizes[2] / (128 * 128);
    const int NB = (N + 255) >> 8;   // buckets of 256 dst nodes (N <= 65536)

    char* ws = (char*)d_ws;
    uint*  h2      = (uint*)ws;                           // N*64 uints (bf16 h)
    float* xbuf    = (float*)(h2 + (size_t)N * 64);       // N*128
    float* alpha_s = xbuf + (size_t)N * 128;              // N*4
    float* alpha_d = alpha_s + (size_t)N * 4;             // N*4
    int* bucket_count  = (int*)(alpha_d + (size_t)N * 4); // 256
    int* bucket_base   = bucket_count + 256;              // NB+1 (<=257)
    int* bucket_cursor = bucket_base + 260;               // 256
    int* row_start     = bucket_cursor + 256;             // N+1
    uint* bdata        = (uint*)(row_start + N + 1);      // E
    ushort* csr_src    = (ushort*)(bdata + E);            // E

    const int nbE = (E + 2047) / 2048;

    // ---- CSR build: two-level counting sort (graph is layer-invariant) ----
    zero256_kernel<<<1, 256, 0, stream>>>(bucket_count);
    bucket_count_kernel<<<nbE, 256, 0, stream>>>(ei, E, NB, bucket_count);
    bucket_scan_kernel<<<1, 256, 0, stream>>>(bucket_count, NB, bucket_base,
                                              bucket_cursor, row_start, N);
    distribute_kernel<<<nbE, 256, 0, stream>>>(ei, E, NB, bucket_cursor, bdata);
    bucket_csr_kernel<<<NB, 256, 0, stream>>>(bdata, bucket_base, row_start,
                                              csr_src, N);

    for (int l = 0; l < L; ++l) {
        const float* xin = (l == 0) ? x : xbuf;
        const float* Wl  = W + (size_t)l * 128 * 128;
        const float* asl = att_src + (size_t)l * 128;
        const float* adl = att_dst + (size_t)l * 128;
        const float* bl  = b_conv + (size_t)l * 128;

        gemm_alpha_kernel<<<(N + 63) / 64, 256, 0, stream>>>(
            xin, Wl, asl, adl, h2, alpha_s, alpha_d, N);

        agg_csr_kernel<<<(N * 16 + 255) / 256, 256, 0, stream>>>(
            csr_src, row_start, alpha_s, alpha_d, h2, bl, xbuf, N);
    }

    mlp_kernel<<<(N + 63) / 64, 256, 0, stream>>>(
        xbuf, x, W1, b1, W2, b2, outp, N);
}

// Round 6
// 391.643 us; speedup vs baseline: 24.2821x; 1.0315x over previous
//
#include <hip/hip_runtime.h>

#define NEG_SLOPE 0.2f
#define EPSF 1e-16f

typedef unsigned int uint;
typedef unsigned short ushort;
typedef __attribute__((ext_vector_type(8))) short short8;   // 8 bf16 (4 VGPRs)
typedef __attribute__((ext_vector_type(4))) float floatx4;  // MFMA acc

// RNE float->bf16
static __device__ __forceinline__ ushort f2bf(float f) {
    uint u = __float_as_uint(f);
    return (ushort)((u + 0x7FFFu + ((u >> 16) & 1u)) >> 16);
}
static __device__ __forceinline__ uint pack2(float a, float b) {
    return (uint)f2bf(a) | ((uint)f2bf(b) << 16);
}
static __device__ __forceinline__ float bf_lo(uint p) { return __uint_as_float(p << 16); }
static __device__ __forceinline__ float bf_hi(uint p) { return __uint_as_float(p & 0xFFFF0000u); }
static __device__ __forceinline__ short8 u2s8(uint4 v) {
    union { uint4 u; short8 s; } c; c.u = v; return c.s;
}

// ============================================================ weight prepack (once per call)
// Wp[l]: 2048 uint4 slots; slot = chunk*128+col holds W[l][8*chunk+j][col], j=0..7 (bf16 pairs)
// W1p : 1024 uint4 slots; slot = chunk*32+col holds W1[8*chunk+j][col]
__global__ __launch_bounds__(256) void prepack_w_kernel(
    const float* __restrict__ W, const float* __restrict__ W1,
    uint4* __restrict__ Wp, uint4* __restrict__ W1p, int L)
{
    int id = blockIdx.x * 256 + threadIdx.x;
    int nW = L * 2048;
    if (id < nW) {
        int l = id >> 11, s = id & 2047;
        int chunk = s >> 7, col = s & 127;
        const float* wp = W + (size_t)l * 16384 + (chunk * 8) * 128 + col;
        uint4 pk;
        pk.x = pack2(wp[0],   wp[128]);
        pk.y = pack2(wp[256], wp[384]);
        pk.z = pack2(wp[512], wp[640]);
        pk.w = pack2(wp[768], wp[896]);
        Wp[id] = pk;
    } else if (id < nW + 1024) {
        int s = id - nW;
        int chunk = s >> 5, col = s & 31;
        const float* wp = W1 + (chunk * 8) * 32 + col;
        uint4 pk;
        pk.x = pack2(wp[0],   wp[32]);
        pk.y = pack2(wp[64],  wp[96]);
        pk.z = pack2(wp[128], wp[160]);
        pk.w = pack2(wp[192], wp[224]);
        W1p[s] = pk;
    }
}

// x fp32 [N,128] -> bf16 packed rows [N][16] uint4 (slot c8 = channels 8*c8..8*c8+7)
__global__ __launch_bounds__(256) void prepack_x_kernel(
    const float* __restrict__ x, uint4* __restrict__ xb, int N)
{
    int id = blockIdx.x * 256 + threadIdx.x;
    if (id >= N * 16) return;
    int row = id >> 4, c8 = id & 15;
    const float4* xp = (const float4*)(x + (size_t)row * 128 + c8 * 8);
    float4 v0 = xp[0], v1 = xp[1];
    uint4 pk;
    pk.x = pack2(v0.x, v0.y); pk.y = pack2(v0.z, v0.w);
    pk.z = pack2(v1.x, v1.y); pk.w = pack2(v1.z, v1.w);
    xb[id] = pk;
}

// ============================================================ GEMM + alpha (MFMA)
// xb: bf16 packed rows [N][16] uint4; Wp: prepacked 2048 slots.
// Frag layouts (m89-verified): A[m=lane&15][k=quad*8+j]; B[k][n=lane&15];
// D: col=lane&15, row=quad*4+reg.
#define GA_LDS_BYTES ((2048 + 1040) * 16)   // 49408 > 64*129*4 = 33024
__global__ __launch_bounds__(256) void gemm_alpha_kernel(
    const uint4* __restrict__ xb, const uint4* __restrict__ Wp,
    const float* __restrict__ att_s, const float* __restrict__ att_d,
    uint* __restrict__ h2, float* __restrict__ alpha_s,
    float* __restrict__ alpha_d, int N)
{
    __shared__ __align__(16) char smraw[GA_LDS_BYTES];
    uint4* sW = (uint4*)smraw;            // 2048 slots
    uint4* sX = sW + 2048;                // 16 chunks * 65 slots
    float* sD = (float*)smraw;            // [64][129]

    const int t = threadIdx.x;
    const int rowBase = blockIdx.x * 64;

    // stage W: pure copy (prepacked layout)
#pragma unroll
    for (int i = 0; i < 8; ++i) {
        int slot = t + i * 256;
        sW[slot] = Wp[slot];
    }
    // stage x rows: copy into perm layout [chunk(16)][row(64), pad 65]
#pragma unroll
    for (int i = 0; i < 4; ++i) {
        int f = t + i * 256;              // 0..1023
        int row = f >> 4, c8 = f & 15;
        uint4 v = make_uint4(0u, 0u, 0u, 0u);
        if (rowBase + row < N) v = xb[(size_t)(rowBase + row) * 16 + c8];
        sX[c8 * 65 + row] = v;
    }
    __syncthreads();

    const int w = t >> 6, lane = t & 63, q = lane >> 4, l15 = lane & 15;
    short8 a[4];
#pragma unroll
    for (int s = 0; s < 4; ++s)
        a[s] = u2s8(sX[(4 * s + q) * 65 + 16 * w + l15]);

    floatx4 acc[8];
#pragma unroll
    for (int ct = 0; ct < 8; ++ct) acc[ct] = (floatx4){0.f, 0.f, 0.f, 0.f};
#pragma unroll
    for (int ct = 0; ct < 8; ++ct) {
#pragma unroll
        for (int s = 0; s < 4; ++s) {
            short8 b = u2s8(sW[(4 * s + q) * 128 + 16 * ct + l15]);
            acc[ct] = __builtin_amdgcn_mfma_f32_16x16x32_bf16(a[s], b, acc[ct], 0, 0, 0);
        }
    }
    __syncthreads();

    // D -> LDS fp32 [64][129]
#pragma unroll
    for (int ct = 0; ct < 8; ++ct) {
#pragma unroll
        for (int r = 0; r < 4; ++r)
            sD[(16 * w + 4 * q + r) * 129 + 16 * ct + l15] = acc[ct][r];
    }
    __syncthreads();

    // h2 (packed bf16x2, uint4 = 8 ch) coalesced store
#pragma unroll
    for (int i = 0; i < 4; ++i) {
        int slot = t + i * 256;
        int row = slot >> 4, c8 = slot & 15;
        if (rowBase + row < N) {
            const float* dp = &sD[row * 129 + c8 * 8];
            uint4 o;
            o.x = pack2(dp[0], dp[1]); o.y = pack2(dp[2], dp[3]);
            o.z = pack2(dp[4], dp[5]); o.w = pack2(dp[6], dp[7]);
            ((uint4*)h2)[(size_t)(rowBase + row) * 16 + c8] = o;
        }
    }
    // alphas: thread -> (row = t&63, head = t>>6), fp32 dot over 32 ch
    {
        int row = t & 63, head = t >> 6;
        if (rowBase + row < N) {
            const float* dp = &sD[row * 129 + head * 32];
            const float* asp = att_s + head * 32;
            const float* adp = att_d + head * 32;
            float ps = 0.f, pd = 0.f;
#pragma unroll
            for (int c = 0; c < 32; ++c) { float v = dp[c]; ps += v * asp[c]; pd += v * adp[c]; }
            alpha_s[(size_t)(rowBase + row) * 4 + head] = ps;
            alpha_d[(size_t)(rowBase + row) * 4 + head] = pd;
        }
    }
}

// ============================================================ CSR build: 2-level counting sort
__global__ __launch_bounds__(256) void zero256_kernel(int* __restrict__ p)
{
    p[threadIdx.x] = 0;
}

__global__ __launch_bounds__(256) void bucket_count_kernel(
    const int* __restrict__ ei, int E, int NB, int* __restrict__ bucket_count)
{
    __shared__ int cnt[256];
    cnt[threadIdx.x] = 0;
    __syncthreads();
    const int base = blockIdx.x * 2048 + threadIdx.x;
#pragma unroll
    for (int j = 0; j < 8; ++j) {
        int idx = base + j * 256;
        if (idx < E) atomicAdd(&cnt[ei[E + idx] >> 8], 1);
    }
    __syncthreads();
    int c = cnt[threadIdx.x];
    if (threadIdx.x < NB && c) atomicAdd(&bucket_count[threadIdx.x], c);
}

__global__ __launch_bounds__(256) void bucket_scan_kernel(
    const int* __restrict__ bucket_count, int NB,
    int* __restrict__ bucket_base, int* __restrict__ bucket_cursor,
    int* __restrict__ row_start, int N)
{
    __shared__ int s[256];
    const int t = threadIdx.x;
    int v = (t < NB) ? bucket_count[t] : 0;
    s[t] = v;
    __syncthreads();
    for (int off = 1; off < 256; off <<= 1) {
        int x = s[t];
        int a = (t >= off) ? s[t - off] : 0;
        __syncthreads();
        s[t] = x + a;
        __syncthreads();
    }
    int ex = s[t] - v;
    if (t < NB) { bucket_base[t] = ex; bucket_cursor[t] = ex; }
    if (t == 255) { bucket_base[NB] = s[255]; row_start[N] = s[255]; }
}

__global__ __launch_bounds__(256) void distribute_kernel(
    const int* __restrict__ ei, int E, int NB,
    int* __restrict__ bucket_cursor, uint* __restrict__ bdata)
{
    __shared__ int cnt[256];
    __shared__ int bbase[256];
    cnt[threadIdx.x] = 0;
    __syncthreads();
    const int base = blockIdx.x * 2048 + threadIdx.x;
    int srcs[8], dsts[8], rank[8];
#pragma unroll
    for (int j = 0; j < 8; ++j) {
        int idx = base + j * 256;
        if (idx < E) {
            srcs[j] = ei[idx];
            dsts[j] = ei[E + idx];
            rank[j] = atomicAdd(&cnt[dsts[j] >> 8], 1);
        } else dsts[j] = -1;
    }
    __syncthreads();
    {
        int c = cnt[threadIdx.x];
        bbase[threadIdx.x] = (threadIdx.x < NB && c) ? atomicAdd(&bucket_cursor[threadIdx.x], c) : 0;
    }
    __syncthreads();
#pragma unroll
    for (int j = 0; j < 8; ++j) {
        if (dsts[j] >= 0) {
            int b = dsts[j] >> 8;
            bdata[bbase[b] + rank[j]] = (uint)srcs[j] | ((uint)(dsts[j] & 255) << 16);
        }
    }
}

#define BCAP 12800
__global__ __launch_bounds__(256) void bucket_csr_kernel(
    const uint* __restrict__ bdata, const int* __restrict__ bucket_base,
    int* __restrict__ row_start, ushort* __restrict__ csr_src, int N)
{
    __shared__ int hist[256];
    __shared__ int scn[256];
    __shared__ int cur[256];
    __shared__ ushort buf[BCAP];
    const int b = blockIdx.x;
    const int t = threadIdx.x;
    const int beg = bucket_base[b];
    const int sz = bucket_base[b + 1] - beg;
    hist[t] = 0;
    __syncthreads();
    for (int i = t; i < sz; i += 256) atomicAdd(&hist[bdata[beg + i] >> 16], 1);
    __syncthreads();
    int v = hist[t];
    scn[t] = v;
    __syncthreads();
    for (int off = 1; off < 256; off <<= 1) {
        int x = scn[t];
        int a = (t >= off) ? scn[t - off] : 0;
        __syncthreads();
        scn[t] = x + a;
        __syncthreads();
    }
    int ex = scn[t] - v;
    cur[t] = ex;
    int node = b * 256 + t;
    if (node < N) row_start[node] = beg + ex;
    __syncthreads();
    if (sz <= BCAP) {
        for (int i = t; i < sz; i += 256) {
            uint d = bdata[beg + i];
            int pos = atomicAdd(&cur[d >> 16], 1);
            buf[pos] = (ushort)(d & 0xFFFFu);
        }
        __syncthreads();
        for (int i = t; i < sz; i += 256) csr_src[beg + i] = buf[i];
    } else {
        for (int i = t; i < sz; i += 256) {
            uint d = bdata[beg + i];
            int pos = atomicAdd(&cur[d >> 16], 1);
            csr_src[beg + pos] = (ushort)(d & 0xFFFFu);
        }
    }
}

// ============================================================ fused softmax+aggregate
// 16 lanes per dst node; lane l owns channels 8l..8l+7 (head = l>>2); 2-wide unroll.
// Output written as packed bf16 rows (bit-identical to downstream bf16 staging).
__global__ __launch_bounds__(256) void agg_csr_kernel(
    const ushort* __restrict__ csr_src, const int* __restrict__ row_start,
    const float* __restrict__ alpha_s, const float* __restrict__ alpha_d,
    const uint* __restrict__ h2, const float* __restrict__ b,
    uint4* __restrict__ outb, int N)
{
    const int g = (blockIdx.x * 256 + threadIdx.x) >> 4;
    const int l = threadIdx.x & 15;
    if (g >= N) return;
    const int head = l >> 2;
    const uint4* h4 = (const uint4*)h2;

    const float ad = alpha_d[g * 4 + head];

    // self loop
    float e = alpha_s[g * 4 + head] + ad;
    e = e > 0.f ? e : NEG_SLOPE * e;
    float ex = __expf(e);
    uint4 q = h4[(size_t)g * 16 + l];
    float a0 = ex * bf_lo(q.x), a1 = ex * bf_hi(q.x);
    float a2 = ex * bf_lo(q.y), a3 = ex * bf_hi(q.y);
    float a4 = ex * bf_lo(q.z), a5 = ex * bf_hi(q.z);
    float a6 = ex * bf_lo(q.w), a7 = ex * bf_hi(q.w);
    float sx = ex;

    const int beg = row_start[g];
    const int end = row_start[g + 1];
    int k = beg;
    for (; k + 2 <= end; k += 2) {
        int s0 = csr_src[k], s1 = csr_src[k + 1];
        float e0 = alpha_s[s0 * 4 + head] + ad;
        float e1 = alpha_s[s1 * 4 + head] + ad;
        uint4 q0 = h4[(size_t)s0 * 16 + l];
        uint4 q1 = h4[(size_t)s1 * 16 + l];
        e0 = e0 > 0.f ? e0 : NEG_SLOPE * e0;
        e1 = e1 > 0.f ? e1 : NEG_SLOPE * e1;
        float x0 = __expf(e0), x1 = __expf(e1);
        a0 += x0 * bf_lo(q0.x) + x1 * bf_lo(q1.x);
        a1 += x0 * bf_hi(q0.x) + x1 * bf_hi(q1.x);
        a2 += x0 * bf_lo(q0.y) + x1 * bf_lo(q1.y);
        a3 += x0 * bf_hi(q0.y) + x1 * bf_hi(q1.y);
        a4 += x0 * bf_lo(q0.z) + x1 * bf_lo(q1.z);
        a5 += x0 * bf_hi(q0.z) + x1 * bf_hi(q1.z);
        a6 += x0 * bf_lo(q0.w) + x1 * bf_lo(q1.w);
        a7 += x0 * bf_hi(q0.w) + x1 * bf_hi(q1.w);
        sx += x0 + x1;
    }
    if (k < end) {
        int s0 = csr_src[k];
        float e0 = alpha_s[s0 * 4 + head] + ad;
        uint4 q0 = h4[(size_t)s0 * 16 + l];
        e0 = e0 > 0.f ? e0 : NEG_SLOPE * e0;
        float x0 = __expf(e0);
        a0 += x0 * bf_lo(q0.x); a1 += x0 * bf_hi(q0.x);
        a2 += x0 * bf_lo(q0.y); a3 += x0 * bf_hi(q0.y);
        a4 += x0 * bf_lo(q0.z); a5 += x0 * bf_hi(q0.z);
        a6 += x0 * bf_lo(q0.w); a7 += x0 * bf_hi(q0.w);
        sx += x0;
    }
    const float inv = 1.f / (sx + EPSF);
    const float4 b0 = ((const float4*)b)[l * 2];
    const float4 b1 = ((const float4*)b)[l * 2 + 1];
    uint4 o;
    o.x = pack2(b0.x + a0 * inv, b0.y + a1 * inv);
    o.y = pack2(b0.z + a2 * inv, b0.w + a3 * inv);
    o.z = pack2(b1.x + a4 * inv, b1.y + a5 * inv);
    o.w = pack2(b1.z + a6 * inv, b1.w + a7 * inv);
    outb[(size_t)g * 16 + l] = o;
}

// ============================================================ MLP head (MFMA)
// A = [xb3 | xb0] (bf16 packed rows), B = W1p prepacked.
__global__ __launch_bounds__(256) void mlp_kernel(
    const uint4* __restrict__ xb3, const uint4* __restrict__ xb0,
    const uint4* __restrict__ W1p, const float* __restrict__ b1,
    const float* __restrict__ W2, const float* __restrict__ b2,
    float* __restrict__ out, int N)
{
    __shared__ __align__(16) uint4 sA[32 * 65];
    __shared__ __align__(16) uint4 sB[32 * 32];
    const int t = threadIdx.x;
    const int rowBase = blockIdx.x * 64;

#pragma unroll
    for (int i = 0; i < 8; ++i) {
        int f = t + i * 256;                 // 0..2047
        int c = f & 31, row = f >> 5;
        uint4 v = make_uint4(0u, 0u, 0u, 0u);
        int grow = rowBase + row;
        if (grow < N)
            v = (c < 16) ? xb3[(size_t)grow * 16 + c]
                         : xb0[(size_t)grow * 16 + (c - 16)];
        sA[c * 65 + row] = v;
    }
#pragma unroll
    for (int i = 0; i < 4; ++i) {
        int slot = t + i * 256;
        sB[slot] = W1p[slot];
    }
    __syncthreads();

    const int w = t >> 6, lane = t & 63, q = lane >> 4, l15 = lane & 15;
    floatx4 acc0 = (floatx4){0.f, 0.f, 0.f, 0.f};
    floatx4 acc1 = (floatx4){0.f, 0.f, 0.f, 0.f};
#pragma unroll
    for (int s = 0; s < 8; ++s) {
        short8 a = u2s8(sA[(4 * s + q) * 65 + 16 * w + l15]);
        acc0 = __builtin_amdgcn_mfma_f32_16x16x32_bf16(a, u2s8(sB[(4 * s + q) * 32 + l15]), acc0, 0, 0, 0);
        acc1 = __builtin_amdgcn_mfma_f32_16x16x32_bf16(a, u2s8(sB[(4 * s + q) * 32 + 16 + l15]), acc1, 0, 0, 0);
    }
    const float b1a = b1[l15], b1b = b1[16 + l15];
    const float w2a = W2[l15], w2b = W2[16 + l15];
    const float b2v = b2[0];
#pragma unroll
    for (int r = 0; r < 4; ++r) {
        int row = rowBase + 16 * w + 4 * q + r;
        float v0 = acc0[r] + b1a; v0 = v0 > 0.f ? v0 : 0.f;
        float v1 = acc1[r] + b1b; v1 = v1 > 0.f ? v1 : 0.f;
        float p = v0 * w2a + v1 * w2b;
        p += __shfl_xor(p, 1);
        p += __shfl_xor(p, 2);
        p += __shfl_xor(p, 4);
        p += __shfl_xor(p, 8);
        if (l15 == 0 && row < N)
            out[row] = 1.f / (1.f + __expf(-(p + b2v)));
    }
}

// ============================================================ launch
extern "C" void kernel_launch(void* const* d_in, const int* in_sizes, int n_in,
                              void* d_out, int out_size, void* d_ws, size_t ws_size,
                              hipStream_t stream)
{
    const float* x       = (const float*)d_in[0];
    const int*   ei      = (const int*)d_in[1];
    const float* W       = (const float*)d_in[2];
    const float* att_src = (const float*)d_in[3];
    const float* att_dst = (const float*)d_in[4];
    const float* b_conv  = (const float*)d_in[5];
    const float* W1      = (const float*)d_in[6];
    const float* b1      = (const float*)d_in[7];
    const float* W2      = (const float*)d_in[8];
    const float* b2      = (const float*)d_in[9];
    float* outp = (float*)d_out;

    const int N = in_sizes[0] / 128;
    const int E = in_sizes[1] / 2;
    const int L = in_sizes[2] / (128 * 128);
    const int NB = (N + 255) >> 8;

    char* ws = (char*)d_ws;
    uint*  h2      = (uint*)ws;                           // N*64 uints
    uint4* xb0     = (uint4*)(h2 + (size_t)N * 64);       // N*16 uint4 (bf16 x)
    uint4* xb      = xb0 + (size_t)N * 16;                // N*16 uint4 (layer buf)
    float* alpha_s = (float*)(xb + (size_t)N * 16);       // N*4
    float* alpha_d = alpha_s + (size_t)N * 4;             // N*4
    uint4* Wp      = (uint4*)(alpha_d + (size_t)N * 4);   // L*2048
    uint4* W1p     = Wp + (size_t)L * 2048;               // 1024
    int* bucket_count  = (int*)(W1p + 1024);              // 256
    int* bucket_base   = bucket_count + 256;              // NB+1
    int* bucket_cursor = bucket_base + 260;               // 256
    int* row_start     = bucket_cursor + 256;             // N+1
    uint* bdata        = (uint*)(row_start + N + 1);      // E
    ushort* csr_src    = (ushort*)(bdata + E);            // E

    const int nbE = (E + 2047) / 2048;

    // ---- prepack (once per call) ----
    prepack_w_kernel<<<(L * 2048 + 1024 + 255) / 256, 256, 0, stream>>>(
        W, W1, Wp, W1p, L);
    prepack_x_kernel<<<(N * 16 + 255) / 256, 256, 0, stream>>>(x, xb0, N);

    // ---- CSR build: two-level counting sort ----
    zero256_kernel<<<1, 256, 0, stream>>>(bucket_count);
    bucket_count_kernel<<<nbE, 256, 0, stream>>>(ei, E, NB, bucket_count);
    bucket_scan_kernel<<<1, 256, 0, stream>>>(bucket_count, NB, bucket_base,
                                              bucket_cursor, row_start, N);
    distribute_kernel<<<nbE, 256, 0, stream>>>(ei, E, NB, bucket_cursor, bdata);
    bucket_csr_kernel<<<NB, 256, 0, stream>>>(bdata, bucket_base, row_start,
                                              csr_src, N);

    for (int l = 0; l < L; ++l) {
        const uint4* xin = (l == 0) ? xb0 : xb;
        const uint4* Wl  = Wp + (size_t)l * 2048;
        const float* asl = att_src + (size_t)l * 128;
        const float* adl = att_dst + (size_t)l * 128;
        const float* bl  = b_conv + (size_t)l * 128;

        gemm_alpha_kernel<<<(N + 63) / 64, 256, 0, stream>>>(
            xin, Wl, asl, adl, h2, alpha_s, alpha_d, N);

        agg_csr_kernel<<<(N * 16 + 255) / 256, 256, 0, stream>>>(
            csr_src, row_start, alpha_s, alpha_d, h2, bl, xb, N);
    }

    mlp_kernel<<<(N + 63) / 64, 256, 0, stream>>>(
        xb, xb0, W1p, b1, W2, b2, outp, N);
}

// Round 7
// 387.688 us; speedup vs baseline: 24.5298x; 1.0102x over previous
//
#include <hip/hip_runtime.h>

#define NEG_SLOPE 0.2f
#define EPSF 1e-16f

typedef unsigned int uint;
typedef unsigned short ushort;
typedef __attribute__((ext_vector_type(8))) short short8;   // 8 bf16 (4 VGPRs)
typedef __attribute__((ext_vector_type(4))) float floatx4;  // MFMA acc

// RNE float->bf16
static __device__ __forceinline__ ushort f2bf(float f) {
    uint u = __float_as_uint(f);
    return (ushort)((u + 0x7FFFu + ((u >> 16) & 1u)) >> 16);
}
static __device__ __forceinline__ uint pack2(float a, float b) {
    return (uint)f2bf(a) | ((uint)f2bf(b) << 16);
}
static __device__ __forceinline__ float bf_lo(uint p) { return __uint_as_float(p << 16); }
static __device__ __forceinline__ float bf_hi(uint p) { return __uint_as_float(p & 0xFFFF0000u); }
static __device__ __forceinline__ short8 u2s8(uint4 v) {
    union { uint4 u; short8 s; } c; c.u = v; return c.s;
}
// async global->LDS, 16B per lane, dst = wave-uniform base + lane*16
static __device__ __forceinline__ void load_lds16(const void* g, void* l) {
    __builtin_amdgcn_global_load_lds(
        (const __attribute__((address_space(1))) void*)g,
        (__attribute__((address_space(3))) void*)l, 16, 0, 0);
}

// ============================================================ prep (fused, once per call)
// [0,nW): Wp pack; [nW,nW+1024): W1p pack; then xb pack; last 256: zero bucket_count
__global__ __launch_bounds__(256) void prep_kernel(
    const float* __restrict__ W, const float* __restrict__ W1,
    const float* __restrict__ x, uint4* __restrict__ Wp,
    uint4* __restrict__ W1p, uint4* __restrict__ xb,
    int* __restrict__ bucket_count, int L, int N)
{
    int id = blockIdx.x * 256 + threadIdx.x;
    const int nW = L * 2048;
    const int nX = N * 16;
    if (id < nW) {
        int l = id >> 11, s = id & 2047;
        int chunk = s >> 7, col = s & 127;
        const float* wp = W + (size_t)l * 16384 + (chunk * 8) * 128 + col;
        uint4 pk;
        pk.x = pack2(wp[0],   wp[128]);
        pk.y = pack2(wp[256], wp[384]);
        pk.z = pack2(wp[512], wp[640]);
        pk.w = pack2(wp[768], wp[896]);
        Wp[id] = pk;
    } else if (id < nW + 1024) {
        int s = id - nW;
        int chunk = s >> 5, col = s & 31;
        const float* wp = W1 + (chunk * 8) * 32 + col;
        uint4 pk;
        pk.x = pack2(wp[0],   wp[32]);
        pk.y = pack2(wp[64],  wp[96]);
        pk.z = pack2(wp[128], wp[160]);
        pk.w = pack2(wp[192], wp[224]);
        W1p[s] = pk;
    } else if (id < nW + 1024 + nX) {
        int xid = id - nW - 1024;
        int row = xid >> 4, c8 = xid & 15;
        const float4* xp = (const float4*)(x + (size_t)row * 128 + c8 * 8);
        float4 v0 = xp[0], v1 = xp[1];
        uint4 pk;
        pk.x = pack2(v0.x, v0.y); pk.y = pack2(v0.z, v0.w);
        pk.z = pack2(v1.x, v1.y); pk.w = pack2(v1.z, v1.w);
        xb[xid] = pk;
    } else if (id < nW + 1024 + nX + 256) {
        bucket_count[id - nW - 1024 - nX] = 0;
    }
}

// ============================================================ GEMM + alpha (MFMA)
#define GA_LDS_BYTES ((2048 + 1040) * 16)   // 49408 > 64*129*4 = 33024
__global__ __launch_bounds__(256) void gemm_alpha_kernel(
    const uint4* __restrict__ xb, const uint4* __restrict__ Wp,
    const float* __restrict__ att_s, const float* __restrict__ att_d,
    uint* __restrict__ h2, float* __restrict__ alpha_s,
    float* __restrict__ alpha_d, int N)
{
    __shared__ __align__(16) char smraw[GA_LDS_BYTES];
    uint4* sW = (uint4*)smraw;            // 2048 slots (linear copy of Wp)
    uint4* sX = sW + 2048;                // 16 chunks * 65 slots
    float* sD = (float*)smraw;            // [64][129]

    const int t = threadIdx.x;
    const int wb = t & ~63;               // wave base in [0,256)
    const int rowBase = blockIdx.x * 64;

    // stage W via async global->LDS (layout is an exact linear copy)
#pragma unroll
    for (int i = 0; i < 8; ++i)
        load_lds16(Wp + i * 256 + t, sW + i * 256 + wb);

    // stage x rows: copy into perm layout [chunk(16)][row(64), pad 65]
#pragma unroll
    for (int i = 0; i < 4; ++i) {
        int f = t + i * 256;              // 0..1023
        int row = f >> 4, c8 = f & 15;
        uint4 v = make_uint4(0u, 0u, 0u, 0u);
        if (rowBase + row < N) v = xb[(size_t)(rowBase + row) * 16 + c8];
        sX[c8 * 65 + row] = v;
    }
    __syncthreads();

    const int w = t >> 6, lane = t & 63, q = lane >> 4, l15 = lane & 15;
    short8 a[4];
#pragma unroll
    for (int s = 0; s < 4; ++s)
        a[s] = u2s8(sX[(4 * s + q) * 65 + 16 * w + l15]);

    floatx4 acc[8];
#pragma unroll
    for (int ct = 0; ct < 8; ++ct) acc[ct] = (floatx4){0.f, 0.f, 0.f, 0.f};
#pragma unroll
    for (int ct = 0; ct < 8; ++ct) {
#pragma unroll
        for (int s = 0; s < 4; ++s) {
            short8 b = u2s8(sW[(4 * s + q) * 128 + 16 * ct + l15]);
            acc[ct] = __builtin_amdgcn_mfma_f32_16x16x32_bf16(a[s], b, acc[ct], 0, 0, 0);
        }
    }
    __syncthreads();

    // D -> LDS fp32 [64][129]
#pragma unroll
    for (int ct = 0; ct < 8; ++ct) {
#pragma unroll
        for (int r = 0; r < 4; ++r)
            sD[(16 * w + 4 * q + r) * 129 + 16 * ct + l15] = acc[ct][r];
    }
    __syncthreads();

    // h2 (packed bf16x2, uint4 = 8 ch) coalesced store
#pragma unroll
    for (int i = 0; i < 4; ++i) {
        int slot = t + i * 256;
        int row = slot >> 4, c8 = slot & 15;
        if (rowBase + row < N) {
            const float* dp = &sD[row * 129 + c8 * 8];
            uint4 o;
            o.x = pack2(dp[0], dp[1]); o.y = pack2(dp[2], dp[3]);
            o.z = pack2(dp[4], dp[5]); o.w = pack2(dp[6], dp[7]);
            ((uint4*)h2)[(size_t)(rowBase + row) * 16 + c8] = o;
        }
    }
    // alphas: thread -> (row = t&63, head = t>>6), fp32 dot over 32 ch
    {
        int row = t & 63, head = t >> 6;
        if (rowBase + row < N) {
            const float* dp = &sD[row * 129 + head * 32];
            const float* asp = att_s + head * 32;
            const float* adp = att_d + head * 32;
            float ps = 0.f, pd = 0.f;
#pragma unroll
            for (int c = 0; c < 32; ++c) { float v = dp[c]; ps += v * asp[c]; pd += v * adp[c]; }
            alpha_s[(size_t)(rowBase + row) * 4 + head] = ps;
            alpha_d[(size_t)(rowBase + row) * 4 + head] = pd;
        }
    }
}

// ============================================================ CSR build: 2-level counting sort
__global__ __launch_bounds__(256) void bucket_count_kernel(
    const int* __restrict__ ei, int E, int NB, int* __restrict__ bucket_count)
{
    __shared__ int cnt[256];
    cnt[threadIdx.x] = 0;
    __syncthreads();
    const int base = blockIdx.x * 2048 + threadIdx.x;
#pragma unroll
    for (int j = 0; j < 8; ++j) {
        int idx = base + j * 256;
        if (idx < E) atomicAdd(&cnt[ei[E + idx] >> 8], 1);
    }
    __syncthreads();
    int c = cnt[threadIdx.x];
    if (threadIdx.x < NB && c) atomicAdd(&bucket_count[threadIdx.x], c);
}

__global__ __launch_bounds__(256) void bucket_scan_kernel(
    const int* __restrict__ bucket_count, int NB,
    int* __restrict__ bucket_base, int* __restrict__ bucket_cursor,
    int* __restrict__ row_start, int N)
{
    __shared__ int s[256];
    const int t = threadIdx.x;
    int v = (t < NB) ? bucket_count[t] : 0;
    s[t] = v;
    __syncthreads();
    for (int off = 1; off < 256; off <<= 1) {
        int x = s[t];
        int a = (t >= off) ? s[t - off] : 0;
        __syncthreads();
        s[t] = x + a;
        __syncthreads();
    }
    int ex = s[t] - v;
    if (t < NB) { bucket_base[t] = ex; bucket_cursor[t] = ex; }
    if (t == 255) { bucket_base[NB] = s[255]; row_start[N] = s[255]; }
}

__global__ __launch_bounds__(256) void distribute_kernel(
    const int* __restrict__ ei, int E, int NB,
    int* __restrict__ bucket_cursor, uint* __restrict__ bdata)
{
    __shared__ int cnt[256];
    __shared__ int bbase[256];
    cnt[threadIdx.x] = 0;
    __syncthreads();
    const int base = blockIdx.x * 2048 + threadIdx.x;
    int srcs[8], dsts[8], rank[8];
#pragma unroll
    for (int j = 0; j < 8; ++j) {
        int idx = base + j * 256;
        if (idx < E) {
            srcs[j] = ei[idx];
            dsts[j] = ei[E + idx];
            rank[j] = atomicAdd(&cnt[dsts[j] >> 8], 1);
        } else dsts[j] = -1;
    }
    __syncthreads();
    {
        int c = cnt[threadIdx.x];
        bbase[threadIdx.x] = (threadIdx.x < NB && c) ? atomicAdd(&bucket_cursor[threadIdx.x], c) : 0;
    }
    __syncthreads();
#pragma unroll
    for (int j = 0; j < 8; ++j) {
        if (dsts[j] >= 0) {
            int b = dsts[j] >> 8;
            bdata[bbase[b] + rank[j]] = (uint)srcs[j] | ((uint)(dsts[j] & 255) << 16);
        }
    }
}

#define BCAP 12800
__global__ __launch_bounds__(256) void bucket_csr_kernel(
    const uint* __restrict__ bdata, const int* __restrict__ bucket_base,
    int* __restrict__ row_start, ushort* __restrict__ csr_src, int N)
{
    __shared__ int hist[256];
    __shared__ int scn[256];
    __shared__ int cur[256];
    __shared__ ushort buf[BCAP];
    const int b = blockIdx.x;
    const int t = threadIdx.x;
    const int beg = bucket_base[b];
    const int sz = bucket_base[b + 1] - beg;
    hist[t] = 0;
    __syncthreads();
    for (int i = t; i < sz; i += 256) atomicAdd(&hist[bdata[beg + i] >> 16], 1);
    __syncthreads();
    int v = hist[t];
    scn[t] = v;
    __syncthreads();
    for (int off = 1; off < 256; off <<= 1) {
        int x = scn[t];
        int a = (t >= off) ? scn[t - off] : 0;
        __syncthreads();
        scn[t] = x + a;
        __syncthreads();
    }
    int ex = scn[t] - v;
    cur[t] = ex;
    int node = b * 256 + t;
    if (node < N) row_start[node] = beg + ex;
    __syncthreads();
    if (sz <= BCAP) {
        for (int i = t; i < sz; i += 256) {
            uint d = bdata[beg + i];
            int pos = atomicAdd(&cur[d >> 16], 1);
            buf[pos] = (ushort)(d & 0xFFFFu);
        }
        __syncthreads();
        for (int i = t; i < sz; i += 256) csr_src[beg + i] = buf[i];
    } else {
        for (int i = t; i < sz; i += 256) {
            uint d = bdata[beg + i];
            int pos = atomicAdd(&cur[d >> 16], 1);
            csr_src[beg + pos] = (ushort)(d & 0xFFFFu);
        }
    }
}

// ============================================================ fused softmax+aggregate
// 16 lanes per dst node; lane l owns channels 8l..8l+7 (head = l>>2); 4-wide unroll.
__global__ __launch_bounds__(256) void agg_csr_kernel(
    const ushort* __restrict__ csr_src, const int* __restrict__ row_start,
    const float* __restrict__ alpha_s, const float* __restrict__ alpha_d,
    const uint* __restrict__ h2, const float* __restrict__ b,
    uint4* __restrict__ outb, int N)
{
    const int g = (blockIdx.x * 256 + threadIdx.x) >> 4;
    const int l = threadIdx.x & 15;
    if (g >= N) return;
    const int head = l >> 2;
    const uint4* h4 = (const uint4*)h2;

    const float ad = alpha_d[g * 4 + head];

    // self loop
    float e = alpha_s[g * 4 + head] + ad;
    e = e > 0.f ? e : NEG_SLOPE * e;
    float ex = __expf(e);
    uint4 q = h4[(size_t)g * 16 + l];
    float a0 = ex * bf_lo(q.x), a1 = ex * bf_hi(q.x);
    float a2 = ex * bf_lo(q.y), a3 = ex * bf_hi(q.y);
    float a4 = ex * bf_lo(q.z), a5 = ex * bf_hi(q.z);
    float a6 = ex * bf_lo(q.w), a7 = ex * bf_hi(q.w);
    float sx = ex;

    const int beg = row_start[g];
    const int end = row_start[g + 1];
    int k = beg;
    for (; k + 4 <= end; k += 4) {
        int s0 = csr_src[k], s1 = csr_src[k + 1];
        int s2 = csr_src[k + 2], s3 = csr_src[k + 3];
        uint4 q0 = h4[(size_t)s0 * 16 + l];
        uint4 q1 = h4[(size_t)s1 * 16 + l];
        uint4 q2 = h4[(size_t)s2 * 16 + l];
        uint4 q3 = h4[(size_t)s3 * 16 + l];
        float e0 = alpha_s[s0 * 4 + head] + ad;
        float e1 = alpha_s[s1 * 4 + head] + ad;
        float e2 = alpha_s[s2 * 4 + head] + ad;
        float e3 = alpha_s[s3 * 4 + head] + ad;
        e0 = e0 > 0.f ? e0 : NEG_SLOPE * e0;
        e1 = e1 > 0.f ? e1 : NEG_SLOPE * e1;
        e2 = e2 > 0.f ? e2 : NEG_SLOPE * e2;
        e3 = e3 > 0.f ? e3 : NEG_SLOPE * e3;
        float x0 = __expf(e0), x1 = __expf(e1);
        float x2 = __expf(e2), x3 = __expf(e3);
        a0 += x0 * bf_lo(q0.x) + x1 * bf_lo(q1.x) + x2 * bf_lo(q2.x) + x3 * bf_lo(q3.x);
        a1 += x0 * bf_hi(q0.x) + x1 * bf_hi(q1.x) + x2 * bf_hi(q2.x) + x3 * bf_hi(q3.x);
        a2 += x0 * bf_lo(q0.y) + x1 * bf_lo(q1.y) + x2 * bf_lo(q2.y) + x3 * bf_lo(q3.y);
        a3 += x0 * bf_hi(q0.y) + x1 * bf_hi(q1.y) + x2 * bf_hi(q2.y) + x3 * bf_hi(q3.y);
        a4 += x0 * bf_lo(q0.z) + x1 * bf_lo(q1.z) + x2 * bf_lo(q2.z) + x3 * bf_lo(q3.z);
        a5 += x0 * bf_hi(q0.z) + x1 * bf_hi(q1.z) + x2 * bf_hi(q2.z) + x3 * bf_hi(q3.z);
        a6 += x0 * bf_lo(q0.w) + x1 * bf_lo(q1.w) + x2 * bf_lo(q2.w) + x3 * bf_lo(q3.w);
        a7 += x0 * bf_hi(q0.w) + x1 * bf_hi(q1.w) + x2 * bf_hi(q2.w) + x3 * bf_hi(q3.w);
        sx += x0 + x1 + x2 + x3;
    }
    for (; k < end; ++k) {
        int s0 = csr_src[k];
        float e0 = alpha_s[s0 * 4 + head] + ad;
        uint4 q0 = h4[(size_t)s0 * 16 + l];
        e0 = e0 > 0.f ? e0 : NEG_SLOPE * e0;
        float x0 = __expf(e0);
        a0 += x0 * bf_lo(q0.x); a1 += x0 * bf_hi(q0.x);
        a2 += x0 * bf_lo(q0.y); a3 += x0 * bf_hi(q0.y);
        a4 += x0 * bf_lo(q0.z); a5 += x0 * bf_hi(q0.z);
        a6 += x0 * bf_lo(q0.w); a7 += x0 * bf_hi(q0.w);
        sx += x0;
    }
    const float inv = 1.f / (sx + EPSF);
    const float4 b0 = ((const float4*)b)[l * 2];
    const float4 b1 = ((const float4*)b)[l * 2 + 1];
    uint4 o;
    o.x = pack2(b0.x + a0 * inv, b0.y + a1 * inv);
    o.y = pack2(b0.z + a2 * inv, b0.w + a3 * inv);
    o.z = pack2(b1.x + a4 * inv, b1.y + a5 * inv);
    o.w = pack2(b1.z + a6 * inv, b1.w + a7 * inv);
    outb[(size_t)g * 16 + l] = o;
}

// ============================================================ MLP head (MFMA)
__global__ __launch_bounds__(256) void mlp_kernel(
    const uint4* __restrict__ xb3, const uint4* __restrict__ xb0,
    const uint4* __restrict__ W1p, const float* __restrict__ b1,
    const float* __restrict__ W2, const float* __restrict__ b2,
    float* __restrict__ out, int N)
{
    __shared__ __align__(16) uint4 sA[32 * 65];
    __shared__ __align__(16) uint4 sB[32 * 32];
    const int t = threadIdx.x;
    const int wb = t & ~63;
    const int rowBase = blockIdx.x * 64;

#pragma unroll
    for (int i = 0; i < 4; ++i)
        load_lds16(W1p + i * 256 + t, sB + i * 256 + wb);
#pragma unroll
    for (int i = 0; i < 8; ++i) {
        int f = t + i * 256;
        int c = f & 31, row = f >> 5;
        uint4 v = make_uint4(0u, 0u, 0u, 0u);
        int grow = rowBase + row;
        if (grow < N)
            v = (c < 16) ? xb3[(size_t)grow * 16 + c]
                         : xb0[(size_t)grow * 16 + (c - 16)];
        sA[c * 65 + row] = v;
    }
    __syncthreads();

    const int w = t >> 6, lane = t & 63, q = lane >> 4, l15 = lane & 15;
    floatx4 acc0 = (floatx4){0.f, 0.f, 0.f, 0.f};
    floatx4 acc1 = (floatx4){0.f, 0.f, 0.f, 0.f};
#pragma unroll
    for (int s = 0; s < 8; ++s) {
        short8 a = u2s8(sA[(4 * s + q) * 65 + 16 * w + l15]);
        acc0 = __builtin_amdgcn_mfma_f32_16x16x32_bf16(a, u2s8(sB[(4 * s + q) * 32 + l15]), acc0, 0, 0, 0);
        acc1 = __builtin_amdgcn_mfma_f32_16x16x32_bf16(a, u2s8(sB[(4 * s + q) * 32 + 16 + l15]), acc1, 0, 0, 0);
    }
    const float b1a = b1[l15], b1b = b1[16 + l15];
    const float w2a = W2[l15], w2b = W2[16 + l15];
    const float b2v = b2[0];
#pragma unroll
    for (int r = 0; r < 4; ++r) {
        int row = rowBase + 16 * w + 4 * q + r;
        float v0 = acc0[r] + b1a; v0 = v0 > 0.f ? v0 : 0.f;
        float v1 = acc1[r] + b1b; v1 = v1 > 0.f ? v1 : 0.f;
        float p = v0 * w2a + v1 * w2b;
        p += __shfl_xor(p, 1);
        p += __shfl_xor(p, 2);
        p += __shfl_xor(p, 4);
        p += __shfl_xor(p, 8);
        if (l15 == 0 && row < N)
            out[row] = 1.f / (1.f + __expf(-(p + b2v)));
    }
}

// ============================================================ launch
extern "C" void kernel_launch(void* const* d_in, const int* in_sizes, int n_in,
                              void* d_out, int out_size, void* d_ws, size_t ws_size,
                              hipStream_t stream)
{
    const float* x       = (const float*)d_in[0];
    const int*   ei      = (const int*)d_in[1];
    const float* W       = (const float*)d_in[2];
    const float* att_src = (const float*)d_in[3];
    const float* att_dst = (const float*)d_in[4];
    const float* b_conv  = (const float*)d_in[5];
    const float* W1      = (const float*)d_in[6];
    const float* b1      = (const float*)d_in[7];
    const float* W2      = (const float*)d_in[8];
    const float* b2      = (const float*)d_in[9];
    float* outp = (float*)d_out;

    const int N = in_sizes[0] / 128;
    const int E = in_sizes[1] / 2;
    const int L = in_sizes[2] / (128 * 128);
    const int NB = (N + 255) >> 8;

    char* ws = (char*)d_ws;
    uint*  h2      = (uint*)ws;                           // N*64 uints
    uint4* xb0     = (uint4*)(h2 + (size_t)N * 64);       // N*16 uint4 (bf16 x)
    uint4* xb      = xb0 + (size_t)N * 16;                // N*16 uint4 (layer buf)
    float* alpha_s = (float*)(xb + (size_t)N * 16);       // N*4
    float* alpha_d = alpha_s + (size_t)N * 4;             // N*4
    uint4* Wp      = (uint4*)(alpha_d + (size_t)N * 4);   // L*2048
    uint4* W1p     = Wp + (size_t)L * 2048;               // 1024
    int* bucket_count  = (int*)(W1p + 1024);              // 256
    int* bucket_base   = bucket_count + 256;              // NB+1
    int* bucket_cursor = bucket_base + 260;               // 256
    int* row_start     = bucket_cursor + 256;             // N+1
    uint* bdata        = (uint*)(row_start + N + 1);      // E
    ushort* csr_src    = (ushort*)(bdata + E);            // E

    const int nbE = (E + 2047) / 2048;
    const int prepItems = L * 2048 + 1024 + N * 16 + 256;

    // ---- prep: pack weights + x, zero bucket counters (one kernel) ----
    prep_kernel<<<(prepItems + 255) / 256, 256, 0, stream>>>(
        W, W1, x, Wp, W1p, xb0, bucket_count, L, N);

    // ---- CSR build: two-level counting sort ----
    bucket_count_kernel<<<nbE, 256, 0, stream>>>(ei, E, NB, bucket_count);
    bucket_scan_kernel<<<1, 256, 0, stream>>>(bucket_count, NB, bucket_base,
                                              bucket_cursor, row_start, N);
    distribute_kernel<<<nbE, 256, 0, stream>>>(ei, E, NB, bucket_cursor, bdata);
    bucket_csr_kernel<<<NB, 256, 0, stream>>>(bdata, bucket_base, row_start,
                                              csr_src, N);

    for (int l = 0; l < L; ++l) {
        const uint4* xin = (l == 0) ? xb0 : xb;
        const uint4* Wl  = Wp + (size_t)l * 2048;
        const float* asl = att_src + (size_t)l * 128;
        const float* adl = att_dst + (size_t)l * 128;
        const float* bl  = b_conv + (size_t)l * 128;

        gemm_alpha_kernel<<<(N + 63) / 64, 256, 0, stream>>>(
            xin, Wl, asl, adl, h2, alpha_s, alpha_d, N);

        agg_csr_kernel<<<(N * 16 + 255) / 256, 256, 0, stream>>>(
            csr_src, row_start, alpha_s, alpha_d, h2, bl, xb, N);
    }

    mlp_kernel<<<(N + 63) / 64, 256, 0, stream>>>(
        xb, xb0, W1p, b1, W2, b2, outp, N);
}

// Round 9
// 359.822 us; speedup vs baseline: 26.4295x; 1.0774x over previous
//
#include <hip/hip_runtime.h>

#define NEG_SLOPE 0.2f
#define EPSF 1e-16f
#define SEG_SHIFT 13   // src segment = src >> 13 (8192 rows = 2 MB of h2)

typedef unsigned int uint;
typedef unsigned short ushort;
typedef __attribute__((ext_vector_type(8))) short short8;   // 8 bf16 (4 VGPRs)
typedef __attribute__((ext_vector_type(4))) float floatx4;  // MFMA acc
typedef __attribute__((ext_vector_type(4))) uint uintx4;    // for nontemporal store

// RNE float->bf16
static __device__ __forceinline__ ushort f2bf(float f) {
    uint u = __float_as_uint(f);
    return (ushort)((u + 0x7FFFu + ((u >> 16) & 1u)) >> 16);
}
static __device__ __forceinline__ uint pack2(float a, float b) {
    return (uint)f2bf(a) | ((uint)f2bf(b) << 16);
}
static __device__ __forceinline__ float bf_lo(uint p) { return __uint_as_float(p << 16); }
static __device__ __forceinline__ float bf_hi(uint p) { return __uint_as_float(p & 0xFFFF0000u); }
static __device__ __forceinline__ short8 u2s8(uint4 v) {
    union { uint4 u; short8 s; } c; c.u = v; return c.s;
}
// async global->LDS, 16B per lane, dst = wave-uniform base + lane*16
static __device__ __forceinline__ void load_lds16(const void* g, void* l) {
    __builtin_amdgcn_global_load_lds(
        (const __attribute__((address_space(1))) void*)g,
        (__attribute__((address_space(3))) void*)l, 16, 0, 0);
}

// ============================================================ prep + bucket count (fused)
// Blocks [0,nbPrep): pack Wp/W1p/xb. Blocks [nbPrep,..): LDS histogram of dst>>8.
__global__ __launch_bounds__(256) void prep_count_kernel(
    const float* __restrict__ W, const float* __restrict__ W1,
    const float* __restrict__ x, uint4* __restrict__ Wp,
    uint4* __restrict__ W1p, uint4* __restrict__ xb,
    const int* __restrict__ ei, int E, int NB,
    int* __restrict__ bucket_count, int L, int N, int nbPrep)
{
    __shared__ int cnt[256];
    if ((int)blockIdx.x >= nbPrep) {
        cnt[threadIdx.x] = 0;
        __syncthreads();
        const int base = (blockIdx.x - nbPrep) * 2048 + threadIdx.x;
#pragma unroll
        for (int j = 0; j < 8; ++j) {
            int idx = base + j * 256;
            if (idx < E) atomicAdd(&cnt[ei[E + idx] >> 8], 1);
        }
        __syncthreads();
        int c = cnt[threadIdx.x];
        if ((int)threadIdx.x < NB && c) atomicAdd(&bucket_count[threadIdx.x], c);
        return;
    }
    int id = blockIdx.x * 256 + threadIdx.x;
    const int nW = L * 2048;
    const int nX = N * 16;
    if (id < nW) {
        int l = id >> 11, s = id & 2047;
        int chunk = s >> 7, col = s & 127;
        const float* wp = W + (size_t)l * 16384 + (chunk * 8) * 128 + col;
        uint4 pk;
        pk.x = pack2(wp[0],   wp[128]);
        pk.y = pack2(wp[256], wp[384]);
        pk.z = pack2(wp[512], wp[640]);
        pk.w = pack2(wp[768], wp[896]);
        Wp[id] = pk;
    } else if (id < nW + 1024) {
        int s = id - nW;
        int chunk = s >> 5, col = s & 31;
        const float* wp = W1 + (chunk * 8) * 32 + col;
        uint4 pk;
        pk.x = pack2(wp[0],   wp[32]);
        pk.y = pack2(wp[64],  wp[96]);
        pk.z = pack2(wp[128], wp[160]);
        pk.w = pack2(wp[192], wp[224]);
        W1p[s] = pk;
    } else if (id < nW + 1024 + nX) {
        int xid = id - nW - 1024;
        int row = xid >> 4, c8 = xid & 15;
        const float4* xp = (const float4*)(x + (size_t)row * 128 + c8 * 8);
        float4 v0 = xp[0], v1 = xp[1];
        uint4 pk;
        pk.x = pack2(v0.x, v0.y); pk.y = pack2(v0.z, v0.w);
        pk.z = pack2(v1.x, v1.y); pk.w = pack2(v1.z, v1.w);
        xb[xid] = pk;
    }
}

// ============================================================ GEMM + alpha (MFMA)
#define GA_LDS_BYTES ((2048 + 1040) * 16)   // 49408 > 64*129*4 = 33024
__global__ __launch_bounds__(256) void gemm_alpha_kernel(
    const uint4* __restrict__ xb, const uint4* __restrict__ Wp,
    const float* __restrict__ att_s, const float* __restrict__ att_d,
    uint* __restrict__ h2, float* __restrict__ alpha_s,
    float* __restrict__ alpha_d, int N)
{
    __shared__ __align__(16) char smraw[GA_LDS_BYTES];
    uint4* sW = (uint4*)smraw;            // 2048 slots (linear copy of Wp)
    uint4* sX = sW + 2048;                // 16 chunks * 65 slots
    float* sD = (float*)smraw;            // [64][129]

    const int t = threadIdx.x;
    const int wb = t & ~63;
    const int rowBase = blockIdx.x * 64;

#pragma unroll
    for (int i = 0; i < 8; ++i)
        load_lds16(Wp + i * 256 + t, sW + i * 256 + wb);

#pragma unroll
    for (int i = 0; i < 4; ++i) {
        int f = t + i * 256;
        int row = f >> 4, c8 = f & 15;
        uint4 v = make_uint4(0u, 0u, 0u, 0u);
        if (rowBase + row < N) v = xb[(size_t)(rowBase + row) * 16 + c8];
        sX[c8 * 65 + row] = v;
    }
    __syncthreads();

    const int w = t >> 6, lane = t & 63, q = lane >> 4, l15 = lane & 15;
    short8 a[4];
#pragma unroll
    for (int s = 0; s < 4; ++s)
        a[s] = u2s8(sX[(4 * s + q) * 65 + 16 * w + l15]);

    floatx4 acc[8];
#pragma unroll
    for (int ct = 0; ct < 8; ++ct) acc[ct] = (floatx4){0.f, 0.f, 0.f, 0.f};
#pragma unroll
    for (int ct = 0; ct < 8; ++ct) {
#pragma unroll
        for (int s = 0; s < 4; ++s) {
            short8 b = u2s8(sW[(4 * s + q) * 128 + 16 * ct + l15]);
            acc[ct] = __builtin_amdgcn_mfma_f32_16x16x32_bf16(a[s], b, acc[ct], 0, 0, 0);
        }
    }
    __syncthreads();

#pragma unroll
    for (int ct = 0; ct < 8; ++ct) {
#pragma unroll
        for (int r = 0; r < 4; ++r)
            sD[(16 * w + 4 * q + r) * 129 + 16 * ct + l15] = acc[ct][r];
    }
    __syncthreads();

#pragma unroll
    for (int i = 0; i < 4; ++i) {
        int slot = t + i * 256;
        int row = slot >> 4, c8 = slot & 15;
        if (rowBase + row < N) {
            const float* dp = &sD[row * 129 + c8 * 8];
            uint4 o;
            o.x = pack2(dp[0], dp[1]); o.y = pack2(dp[2], dp[3]);
            o.z = pack2(dp[4], dp[5]); o.w = pack2(dp[6], dp[7]);
            ((uint4*)h2)[(size_t)(rowBase + row) * 16 + c8] = o;
        }
    }
    {
        int row = t & 63, head = t >> 6;
        if (rowBase + row < N) {
            const float* dp = &sD[row * 129 + head * 32];
            const float* asp = att_s + head * 32;
            const float* adp = att_d + head * 32;
            float ps = 0.f, pd = 0.f;
#pragma unroll
            for (int c = 0; c < 32; ++c) { float v = dp[c]; ps += v * asp[c]; pd += v * adp[c]; }
            alpha_s[(size_t)(rowBase + row) * 4 + head] = ps;
            alpha_d[(size_t)(rowBase + row) * 4 + head] = pd;
        }
    }
}

// ============================================================ CSR build
__global__ __launch_bounds__(256) void bucket_scan_kernel(
    const int* __restrict__ bucket_count, int NB,
    int* __restrict__ bucket_base, int* __restrict__ bucket_cursor,
    int* __restrict__ row_start, int N)
{
    __shared__ int s[256];
    const int t = threadIdx.x;
    int v = (t < NB) ? bucket_count[t] : 0;
    s[t] = v;
    __syncthreads();
    for (int off = 1; off < 256; off <<= 1) {
        int x = s[t];
        int a = (t >= off) ? s[t - off] : 0;
        __syncthreads();
        s[t] = x + a;
        __syncthreads();
    }
    int ex = s[t] - v;
    if (t < NB) { bucket_base[t] = ex; bucket_cursor[t] = ex; }
    if (t == 255) { bucket_base[NB] = s[255]; row_start[N] = s[255]; }
}

__global__ __launch_bounds__(256) void distribute_kernel(
    const int* __restrict__ ei, int E, int NB,
    int* __restrict__ bucket_cursor, uint* __restrict__ bdata)
{
    __shared__ int cnt[256];
    __shared__ int bbase[256];
    cnt[threadIdx.x] = 0;
    __syncthreads();
    const int base = blockIdx.x * 2048 + threadIdx.x;
    int srcs[8], dsts[8], rank[8];
#pragma unroll
    for (int j = 0; j < 8; ++j) {
        int idx = base + j * 256;
        if (idx < E) {
            srcs[j] = ei[idx];
            dsts[j] = ei[E + idx];
            rank[j] = atomicAdd(&cnt[dsts[j] >> 8], 1);
        } else dsts[j] = -1;
    }
    __syncthreads();
    {
        int c = cnt[threadIdx.x];
        bbase[threadIdx.x] = ((int)threadIdx.x < NB && c) ? atomicAdd(&bucket_cursor[threadIdx.x], c) : 0;
    }
    __syncthreads();
#pragma unroll
    for (int j = 0; j < 8; ++j) {
        if (dsts[j] >= 0) {
            int b = dsts[j] >> 8;
            bdata[bbase[b] + rank[j]] = (uint)srcs[j] | ((uint)(dsts[j] & 255) << 16);
        }
    }
}

// One block per bucket. Sort key = (local_dst<<3) | src_segment so each node's
// edge list is grouped by 2MB src segments (L2 locality in agg).
#define BCAP 12800
__global__ __launch_bounds__(256) void bucket_csr_kernel(
    const uint* __restrict__ bdata, const int* __restrict__ bucket_base,
    int* __restrict__ row_start, ushort* __restrict__ csr_src, int N)
{
    __shared__ int hist[2048];
    __shared__ int cur[2048];
    __shared__ int scn[256];
    __shared__ ushort buf[BCAP];
    const int b = blockIdx.x;
    const int t = threadIdx.x;
    const int beg = bucket_base[b];
    const int sz = bucket_base[b + 1] - beg;
#pragma unroll
    for (int j = 0; j < 8; ++j) hist[t * 8 + j] = 0;
    __syncthreads();
    for (int i = t; i < sz; i += 256) {
        uint d = bdata[beg + i];
        int key = (int)((d >> 16) << 3) | (int)((d & 0xFFFFu) >> SEG_SHIFT);
        atomicAdd(&hist[key], 1);
    }
    __syncthreads();
    int local[8]; int s = 0;
#pragma unroll
    for (int j = 0; j < 8; ++j) { local[j] = hist[t * 8 + j]; s += local[j]; }
    scn[t] = s;
    __syncthreads();
    for (int off = 1; off < 256; off <<= 1) {
        int x = scn[t];
        int a = (t >= off) ? scn[t - off] : 0;
        __syncthreads();
        scn[t] = x + a;
        __syncthreads();
    }
    int run = scn[t] - s;
#pragma unroll
    for (int j = 0; j < 8; ++j) { cur[t * 8 + j] = run; run += local[j]; }
    __syncthreads();
    int node = b * 256 + t;
    if (node < N) row_start[node] = beg + cur[t << 3];
    __syncthreads();
    if (sz <= BCAP) {
        for (int i = t; i < sz; i += 256) {
            uint d = bdata[beg + i];
            int key = (int)((d >> 16) << 3) | (int)((d & 0xFFFFu) >> SEG_SHIFT);
            int pos = atomicAdd(&cur[key], 1);
            buf[pos] = (ushort)(d & 0xFFFFu);
        }
        __syncthreads();
        for (int i = t; i < sz; i += 256) csr_src[beg + i] = buf[i];
    } else {
        for (int i = t; i < sz; i += 256) {
            uint d = bdata[beg + i];
            int key = (int)((d >> 16) << 3) | (int)((d & 0xFFFFu) >> SEG_SHIFT);
            int pos = atomicAdd(&cur[key], 1);
            csr_src[beg + pos] = (ushort)(d & 0xFFFFu);
        }
    }
}

// ============================================================ fused softmax+aggregate
// 16 lanes per dst node; lane l owns channels 8l..8l+7 (head = l>>2); 4-wide unroll.
__global__ __launch_bounds__(256) void agg_csr_kernel(
    const ushort* __restrict__ csr_src, const int* __restrict__ row_start,
    const float* __restrict__ alpha_s, const float* __restrict__ alpha_d,
    const uint* __restrict__ h2, const float* __restrict__ b,
    uint* __restrict__ outb, int N)
{
    const int g = (blockIdx.x * 256 + threadIdx.x) >> 4;
    const int l = threadIdx.x & 15;
    if (g >= N) return;
    const int head = l >> 2;
    const uint4* h4 = (const uint4*)h2;

    const float ad = alpha_d[g * 4 + head];

    // self loop
    float e = alpha_s[g * 4 + head] + ad;
    e = e > 0.f ? e : NEG_SLOPE * e;
    float ex = __expf(e);
    uint4 q = h4[(size_t)g * 16 + l];
    float a0 = ex * bf_lo(q.x), a1 = ex * bf_hi(q.x);
    float a2 = ex * bf_lo(q.y), a3 = ex * bf_hi(q.y);
    float a4 = ex * bf_lo(q.z), a5 = ex * bf_hi(q.z);
    float a6 = ex * bf_lo(q.w), a7 = ex * bf_hi(q.w);
    float sx = ex;

    const int beg = row_start[g];
    const int end = row_start[g + 1];
    int k = beg;
    for (; k + 4 <= end; k += 4) {
        int s0 = csr_src[k], s1 = csr_src[k + 1];
        int s2 = csr_src[k + 2], s3 = csr_src[k + 3];
        uint4 q0 = h4[(size_t)s0 * 16 + l];
        uint4 q1 = h4[(size_t)s1 * 16 + l];
        uint4 q2 = h4[(size_t)s2 * 16 + l];
        uint4 q3 = h4[(size_t)s3 * 16 + l];
        float e0 = alpha_s[s0 * 4 + head] + ad;
        float e1 = alpha_s[s1 * 4 + head] + ad;
        float e2 = alpha_s[s2 * 4 + head] + ad;
        float e3 = alpha_s[s3 * 4 + head] + ad;
        e0 = e0 > 0.f ? e0 : NEG_SLOPE * e0;
        e1 = e1 > 0.f ? e1 : NEG_SLOPE * e1;
        e2 = e2 > 0.f ? e2 : NEG_SLOPE * e2;
        e3 = e3 > 0.f ? e3 : NEG_SLOPE * e3;
        float x0 = __expf(e0), x1 = __expf(e1);
        float x2 = __expf(e2), x3 = __expf(e3);
        a0 += x0 * bf_lo(q0.x) + x1 * bf_lo(q1.x) + x2 * bf_lo(q2.x) + x3 * bf_lo(q3.x);
        a1 += x0 * bf_hi(q0.x) + x1 * bf_hi(q1.x) + x2 * bf_hi(q2.x) + x3 * bf_hi(q3.x);
        a2 += x0 * bf_lo(q0.y) + x1 * bf_lo(q1.y) + x2 * bf_lo(q2.y) + x3 * bf_lo(q3.y);
        a3 += x0 * bf_hi(q0.y) + x1 * bf_hi(q1.y) + x2 * bf_hi(q2.y) + x3 * bf_hi(q3.y);
        a4 += x0 * bf_lo(q0.z) + x1 * bf_lo(q1.z) + x2 * bf_lo(q2.z) + x3 * bf_lo(q3.z);
        a5 += x0 * bf_hi(q0.z) + x1 * bf_hi(q1.z) + x2 * bf_hi(q2.z) + x3 * bf_hi(q3.z);
        a6 += x0 * bf_lo(q0.w) + x1 * bf_lo(q1.w) + x2 * bf_lo(q2.w) + x3 * bf_lo(q3.w);
        a7 += x0 * bf_hi(q0.w) + x1 * bf_hi(q1.w) + x2 * bf_hi(q2.w) + x3 * bf_hi(q3.w);
        sx += x0 + x1 + x2 + x3;
    }
    for (; k < end; ++k) {
        int s0 = csr_src[k];
        float e0 = alpha_s[s0 * 4 + head] + ad;
        uint4 q0 = h4[(size_t)s0 * 16 + l];
        e0 = e0 > 0.f ? e0 : NEG_SLOPE * e0;
        float x0 = __expf(e0);
        a0 += x0 * bf_lo(q0.x); a1 += x0 * bf_hi(q0.x);
        a2 += x0 * bf_lo(q0.y); a3 += x0 * bf_hi(q0.y);
        a4 += x0 * bf_lo(q0.z); a5 += x0 * bf_hi(q0.z);
        a6 += x0 * bf_lo(q0.w); a7 += x0 * bf_hi(q0.w);
        sx += x0;
    }
    const float inv = 1.f / (sx + EPSF);
    const float4 b0 = ((const float4*)b)[l * 2];
    const float4 b1 = ((const float4*)b)[l * 2 + 1];
    uintx4 o;
    o.x = pack2(b0.x + a0 * inv, b0.y + a1 * inv);
    o.y = pack2(b0.z + a2 * inv, b0.w + a3 * inv);
    o.z = pack2(b1.x + a4 * inv, b1.y + a5 * inv);
    o.w = pack2(b1.z + a6 * inv, b1.w + a7 * inv);
    __builtin_nontemporal_store(o, (uintx4*)(outb + (size_t)g * 64 + l * 4));
}

// ============================================================ MLP head (MFMA)
__global__ __launch_bounds__(256) void mlp_kernel(
    const uint4* __restrict__ xb3, const uint4* __restrict__ xb0,
    const uint4* __restrict__ W1p, const float* __restrict__ b1,
    const float* __restrict__ W2, const float* __restrict__ b2,
    float* __restrict__ out, int N)
{
    __shared__ __align__(16) uint4 sA[32 * 65];
    __shared__ __align__(16) uint4 sB[32 * 32];
    const int t = threadIdx.x;
    const int wb = t & ~63;
    const int rowBase = blockIdx.x * 64;

#pragma unroll
    for (int i = 0; i < 4; ++i)
        load_lds16(W1p + i * 256 + t, sB + i * 256 + wb);
#pragma unroll
    for (int i = 0; i < 8; ++i) {
        int f = t + i * 256;
        int c = f & 31, row = f >> 5;
        uint4 v = make_uint4(0u, 0u, 0u, 0u);
        int grow = rowBase + row;
        if (grow < N)
            v = (c < 16) ? xb3[(size_t)grow * 16 + c]
                         : xb0[(size_t)grow * 16 + (c - 16)];
        sA[c * 65 + row] = v;
    }
    __syncthreads();

    const int w = t >> 6, lane = t & 63, q = lane >> 4, l15 = lane & 15;
    floatx4 acc0 = (floatx4){0.f, 0.f, 0.f, 0.f};
    floatx4 acc1 = (floatx4){0.f, 0.f, 0.f, 0.f};
#pragma unroll
    for (int s = 0; s < 8; ++s) {
        short8 a = u2s8(sA[(4 * s + q) * 65 + 16 * w + l15]);
        acc0 = __builtin_amdgcn_mfma_f32_16x16x32_bf16(a, u2s8(sB[(4 * s + q) * 32 + l15]), acc0, 0, 0, 0);
        acc1 = __builtin_amdgcn_mfma_f32_16x16x32_bf16(a, u2s8(sB[(4 * s + q) * 32 + 16 + l15]), acc1, 0, 0, 0);
    }
    const float b1a = b1[l15], b1b = b1[16 + l15];
    const float w2a = W2[l15], w2b = W2[16 + l15];
    const float b2v = b2[0];
#pragma unroll
    for (int r = 0; r < 4; ++r) {
        int row = rowBase + 16 * w + 4 * q + r;
        float v0 = acc0[r] + b1a; v0 = v0 > 0.f ? v0 : 0.f;
        float v1 = acc1[r] + b1b; v1 = v1 > 0.f ? v1 : 0.f;
        float p = v0 * w2a + v1 * w2b;
        p += __shfl_xor(p, 1);
        p += __shfl_xor(p, 2);
        p += __shfl_xor(p, 4);
        p += __shfl_xor(p, 8);
        if (l15 == 0 && row < N)
            out[row] = 1.f / (1.f + __expf(-(p + b2v)));
    }
}

// ============================================================ launch
extern "C" void kernel_launch(void* const* d_in, const int* in_sizes, int n_in,
                              void* d_out, int out_size, void* d_ws, size_t ws_size,
                              hipStream_t stream)
{
    const float* x       = (const float*)d_in[0];
    const int*   ei      = (const int*)d_in[1];
    const float* W       = (const float*)d_in[2];
    const float* att_src = (const float*)d_in[3];
    const float* att_dst = (const float*)d_in[4];
    const float* b_conv  = (const float*)d_in[5];
    const float* W1      = (const float*)d_in[6];
    const float* b1      = (const float*)d_in[7];
    const float* W2      = (const float*)d_in[8];
    const float* b2      = (const float*)d_in[9];
    float* outp = (float*)d_out;

    const int N = in_sizes[0] / 128;
    const int E = in_sizes[1] / 2;
    const int L = in_sizes[2] / (128 * 128);
    const int NB = (N + 255) >> 8;

    char* ws = (char*)d_ws;
    uint*  h2      = (uint*)ws;                           // N*64 uints
    uint4* xb0     = (uint4*)(h2 + (size_t)N * 64);       // N*16 uint4 (bf16 x)
    uint4* xb      = xb0 + (size_t)N * 16;                // N*16 uint4 (layer buf)
    float* alpha_s = (float*)(xb + (size_t)N * 16);       // N*4
    float* alpha_d = alpha_s + (size_t)N * 4;             // N*4
    uint4* Wp      = (uint4*)(alpha_d + (size_t)N * 4);   // L*2048
    uint4* W1p     = Wp + (size_t)L * 2048;               // 1024
    int* bucket_count  = (int*)(W1p + 1024);              // 256
    int* bucket_base   = bucket_count + 256;              // NB+1
    int* bucket_cursor = bucket_base + 260;               // 256
    int* row_start     = bucket_cursor + 256;             // N+1
    uint* bdata        = (uint*)(row_start + N + 1);      // E
    ushort* csr_src    = (ushort*)(bdata + E);            // E

    const int nbE = (E + 2047) / 2048;
    const int prepItems = L * 2048 + 1024 + N * 16;
    const int nbPrep = (prepItems + 255) / 256;

    // zero bucket counters (graph-capture-safe memset node)
    (void)hipMemsetAsync(bucket_count, 0, 256 * sizeof(int), stream);

    // ---- prep packing + bucket counting (one kernel) ----
    prep_count_kernel<<<nbPrep + nbE, 256, 0, stream>>>(
        W, W1, x, Wp, W1p, xb0, ei, E, NB, bucket_count, L, N, nbPrep);

    bucket_scan_kernel<<<1, 256, 0, stream>>>(bucket_count, NB, bucket_base,
                                              bucket_cursor, row_start, N);
    distribute_kernel<<<nbE, 256, 0, stream>>>(ei, E, NB, bucket_cursor, bdata);
    bucket_csr_kernel<<<NB, 256, 0, stream>>>(bdata, bucket_base, row_start,
                                              csr_src, N);

    for (int l = 0; l < L; ++l) {
        const uint4* xin = (l == 0) ? xb0 : xb;
        const uint4* Wl  = Wp + (size_t)l * 2048;
        const float* asl = att_src + (size_t)l * 128;
        const float* adl = att_dst + (size_t)l * 128;
        const float* bl  = b_conv + (size_t)l * 128;

        gemm_alpha_kernel<<<(N + 63) / 64, 256, 0, stream>>>(
            xin, Wl, asl, adl, h2, alpha_s, alpha_d, N);

        agg_csr_kernel<<<(N * 16 + 255) / 256, 256, 0, stream>>>(
            csr_src, row_start, alpha_s, alpha_d, h2, bl, (uint*)xb, N);
    }

    mlp_kernel<<<(N + 63) / 64, 256, 0, stream>>>(
        xb, xb0, W1p, b1, W2, b2, outp, N);
}